// Round 4
// baseline (393.656 us; speedup 1.0000x reference)
//
#include <hip/hip_runtime.h>
#include <hip/hip_bf16.h>

typedef __hip_bfloat16 bf16;

__device__ __forceinline__ float bf2f(bf16 h) { return __bfloat162float(h); }
__device__ __forceinline__ bf16 us2bf(unsigned short u) {
  union { unsigned short s; bf16 h; } v; v.s = u; return v.h;
}
__device__ __forceinline__ unsigned int pk2(float a, float b) {
  union { bf16 h; unsigned short u; } ua, ub;
  ua.h = __float2bfloat16(a); ub.h = __float2bfloat16(b);
  return ((unsigned int)ub.u << 16) | (unsigned int)ua.u;
}
__device__ __forceinline__ float asf(unsigned int u) {
  union { unsigned int u; float f; } v; v.u = u; return v.f;
}

#define HH 128
#define WW 128
#define HS 512
#define WSZ 512
#define NC 64
#define QN (HS*WSZ)

// ---- ws float-offset layout ----
#define O_INP    0        // 49152
#define O_ENCW   49152    // 1728
#define O_ENCB   50880    // 64
#define O_W1     50944    // 256
#define O_B1     51200    // 64
#define O_W2     51264    // 4096
#define O_B2     55360    // 64
#define O_RW     55424    // 256
#define O_RB     55680    // 4
#define O_OW     55684    // 128
#define O_OB     55812    // 2
#define O_TW     55814    // 1728
#define O_TB     57542    // 3
#define O_WC     57545    // 2048
#define O_WE     59593    // 2048
#define O_OFFTAB 61696    // 32
#define O_RTAB   61728    // 64
#define O_FLAG   61792    // 1
#define O_CWC    61824    // 16*512 [cls][k][c]
#define O_CWE    70016    // 16*512 [cls][c][k]
#define O_TWP    78208    // 1728 [o][j][c]
#define O_FEAT   81920    // 16384*64 f32 HWC
#define O_PRED   1130496  // 262144*3 f32 HWC

// class-sorted halo decode prefix for 10x18 halo (classes by ((p+3)&3))
// ny = [3,2,2,3] (a), nx = [5,4,4,5] (b); counts = ny*nx
__constant__ int PREF2[16] = {0,15,27,39,54,64,72,80,90,100,108,116,126,141,153,165};

__device__ __forceinline__ float rdin(const void* p, int i, bool f32m) {
  return f32m ? ((const float*)p)[i] : bf2f(((const bf16*)p)[i]);
}

// ---- 0. dtype sniff ----
__global__ void k_sniff(const void* __restrict__ inp, float* __restrict__ ws) {
  int o = threadIdx.x;
  unsigned short u = ((const unsigned short*)inp)[2*o];
  float v = bf2f(us2bf(u));
  bool bf_ok = (v == v) && (fabsf(v) < 64.0f);
  unsigned long long m = __ballot(bf_ok);
  if (o == 0) ws[O_FLAG] = (__popcll(m) >= 48) ? 0.0f : 1.0f;
}

// ---- 1. convert inputs/weights to f32 ----
__global__ __launch_bounds__(256) void k_convert(
    const void* __restrict__ inp, const void* __restrict__ encw, const void* __restrict__ encb,
    const void* __restrict__ w1, const void* __restrict__ b1,
    const void* __restrict__ w2, const void* __restrict__ b2,
    const void* __restrict__ rw, const void* __restrict__ rb,
    const void* __restrict__ ow, const void* __restrict__ ob,
    const void* __restrict__ tw, const void* __restrict__ tb,
    const void* __restrict__ wc, const void* __restrict__ we,
    float* __restrict__ ws) {
  bool f32m = ws[O_FLAG] > 0.5f;
  int i = blockIdx.x*256 + threadIdx.x;
  if (i < 49152) ws[O_INP + i] = rdin(inp, i, f32m);
  if (i < 1728) { ws[O_ENCW + i] = rdin(encw, i, f32m); ws[O_TW + i] = rdin(tw, i, f32m); }
  if (i < 64)   { ws[O_ENCB+i] = rdin(encb,i,f32m); ws[O_B1+i] = rdin(b1,i,f32m); ws[O_B2+i] = rdin(b2,i,f32m); }
  if (i < 256)  { ws[O_W1+i] = rdin(w1,i,f32m); ws[O_RW+i] = rdin(rw,i,f32m); }
  if (i < 4096) ws[O_W2+i] = rdin(w2,i,f32m);
  if (i < 4)    ws[O_RB+i] = rdin(rb,i,f32m);
  if (i < 128)  ws[O_OW+i] = rdin(ow,i,f32m);
  if (i < 2)    ws[O_OB+i] = rdin(ob,i,f32m);
  if (i < 3)    ws[O_TB+i] = rdin(tb,i,f32m);
  if (i < 2048) { ws[O_WC+i] = rdin(wc,i,f32m); ws[O_WE+i] = rdin(we,i,f32m); }
}

// ---- 2. per-class MLP -> off, r; fold into combined weights; transpose tail weights ----
__global__ __launch_bounds__(64) void k_classcombine(float* __restrict__ ws) {
  __shared__ float sh1[64];
  __shared__ float sh2[64];
  __shared__ float shr[4];
  int cls = blockIdx.x;
  int o = threadIdx.x;
  float m = (float)(cls >> 2), n = (float)(cls & 3);
  float ch = (m + 0.5f)*0.25f - 0.5f;
  float cw = (n + 0.5f)*0.25f - 0.5f;
  const float* W1 = ws + O_W1; const float* B1 = ws + O_B1;
  const float* W2 = ws + O_W2; const float* B2 = ws + O_B2;
  float s = W1[o*4+0]*0.25f + W1[o*4+1]*0.25f + W1[o*4+2]*ch + W1[o*4+3]*cw + B1[o];
  sh1[o] = fmaxf(s, 0.0f);
  __syncthreads();
  float s2 = B2[o];
  for (int i = 0; i < 64; i++) s2 = fmaf(W2[o*64+i], sh1[i], s2);
  sh2[o] = fmaxf(s2, 0.0f);
  __syncthreads();
  if (o < 2) {
    const float* OW = ws + O_OW;
    float a = ws[O_OB + o];
    for (int i = 0; i < 64; i++) a = fmaf(OW[o*64+i], sh2[i], a);
    ws[O_OFFTAB + cls*2 + o] = a;
  } else if (o < 6) {
    int e = o - 2;
    const float* RW = ws + O_RW;
    float a = ws[O_RB + e];
    for (int i = 0; i < 64; i++) a = fmaf(RW[e*64+i], sh2[i], a);
    shr[e] = 1.0f / (1.0f + expf(-a));
    ws[O_RTAB + cls*4 + e] = shr[e];
  }
  __syncthreads();
  float r0 = shr[0], r1 = shr[1], r2 = shr[2], r3 = shr[3];
  const float* WC = ws + O_WC;
  const float* WE = ws + O_WE;
  for (int idx = o; idx < 512; idx += 64) {
    float a =       r0 * WC[0*512 + idx];
    a = fmaf(r1, WC[1*512 + idx], a);
    a = fmaf(r2, WC[2*512 + idx], a);
    a = fmaf(r3, WC[3*512 + idx], a);
    ws[O_CWC + cls*512 + idx] = a;
    float b =       r0 * WE[0*512 + idx];
    b = fmaf(r1, WE[1*512 + idx], b);
    b = fmaf(r2, WE[2*512 + idx], b);
    b = fmaf(r3, WE[3*512 + idx], b);
    ws[O_CWE + cls*512 + idx] = b;
  }
  if (cls == 0) {
    for (int idx = o; idx < 1728; idx += 64) {
      int oo = idx / 576;
      int rem = idx - oo*576;
      int jj = rem >> 6;
      int c = rem & 63;
      ws[O_TWP + idx] = ws[O_TW + (oo*64 + c)*9 + jj];
    }
  }
}

// ---- 3. encoder conv 3->64 -> feat HWC f32 (256 blocks x 64 thr) ----
__global__ __launch_bounds__(64) void k_enc(const float* __restrict__ ws, float* __restrict__ feat) {
  int px = blockIdx.x*64 + threadIdx.x;     // 0..16383
  int x = px & 127, y = px >> 7;
  const float* I = ws + O_INP;
  float tp[27];
  #pragma unroll
  for (int ic = 0; ic < 3; ic++) {
    #pragma unroll
    for (int dy = 0; dy < 3; dy++) {
      int yy = y + dy - 1;
      #pragma unroll
      for (int dx = 0; dx < 3; dx++) {
        int xx = x + dx - 1;
        bool ok = (yy >= 0) & (yy < 128) & (xx >= 0) & (xx < 128);
        tp[ic*9 + dy*3 + dx] = ok ? I[ic*16384 + yy*128 + xx] : 0.0f;
      }
    }
  }
  const float* EW = ws + O_ENCW;
  float4* out = (float4*)(feat + (size_t)px*64);
  for (int og = 0; og < 16; og++) {
    float a[4];
    #pragma unroll
    for (int oo = 0; oo < 4; oo++) {
      float acc = ws[O_ENCB + og*4 + oo];
      #pragma unroll
      for (int kk = 0; kk < 27; kk++) acc = fmaf(EW[(og*4 + oo)*27 + kk], tp[kk], acc);
      a[oo] = acc;
    }
    out[og] = make_float4(a[0], a[1], a[2], a[3]);
  }
}

// ---- 4. fused main+tail: tile 8x16, halo 10x18, 4-lane coop phase A ----
__global__ __launch_bounds__(256, 6) void k_maintail(const float* __restrict__ ws, float* __restrict__ pred) {
  __shared__ unsigned int shd[32*181];     // [cp][slot] packed bf16 pairs, 23168 B
  __shared__ unsigned short sof[192];      // pos -> slot
  __shared__ float spart[384];             // tail upper-half partials
  int blk = blockIdx.x;                    // 0..2047
  int xcd = blk & 7, local = blk >> 3;     // XCD-banded tile mapping for L2 locality
  int ty0 = (xcd*8 + (local >> 5)) * 8;
  int tx0 = (local & 31) * 16;
  int t = threadIdx.x;
  int q = t & 3;
  const float4* Fv = (const float4*)(ws + O_FEAT);

  for (int base = 0; base < 192; base += 64) {
    int s = base + (t >> 2);
    if (s >= 180) continue;
    int cls = 0;
    #pragma unroll
    for (int i = 1; i < 16; i++) cls += (s >= PREF2[i]) ? 1 : 0;
    int j = s - PREF2[cls];
    int a = cls >> 2, bb = cls & 3;
    int nx = ((bb == 0) | (bb == 3)) ? 5 : 4;
    int jy = (nx == 4) ? (j >> 2) : ((j*13) >> 6);
    int jx = j - jy*nx;
    int py = ((a + 1) & 3) + 4*jy;
    int px = ((bb + 1) & 3) + 4*jx;
    int pos = py*18 + px;
    if (q == 0) sof[pos] = (unsigned short)s;
    int gy = ty0 - 1 + py, gx = tx0 - 1 + px;
    if ((gy < 0) | (gy >= HS) | (gx < 0) | (gx >= WSZ)) {
      #pragma unroll
      for (int w = 0; w < 8; w++) shd[(q*8 + w)*181 + s] = 0u;
      continue;
    }
    float off0 = ws[O_OFFTAB + cls*2 + 0];
    float off1 = ws[O_OFFTAB + cls*2 + 1];
    float gxf = (((float)gx + 0.5f)*0.25f - 0.5f)*(2.0f/127.0f) - 1.0f + off0*(2.0f/127.0f);
    float gyf = (((float)gy + 0.5f)*0.25f - 0.5f)*(2.0f/127.0f) - 1.0f + off1*(2.0f/127.0f);
    float sx = (gxf + 1.0f)*0.5f*127.0f;
    float sy = (gyf + 1.0f)*0.5f*127.0f;
    float x0f = floorf(sx), y0f = floorf(sy);
    float fx = sx - x0f, fy = sy - y0f;
    int ix0 = (int)x0f, iy0 = (int)y0f;
    int ix1 = ix0 + 1, iy1 = iy0 + 1;
    float wx0 = 1.0f - fx, wy0 = 1.0f - fy;
    float w00 = wy0*wx0, w01 = wy0*fx, w10 = fy*wx0, w11 = fy*fx;
    bool vx0 = (ix0 >= 0) & (ix0 < WW), vx1 = (ix1 >= 0) & (ix1 < WW);
    bool vy0 = (iy0 >= 0) & (iy0 < HH), vy1 = (iy1 >= 0) & (iy1 < HH);
    if (!(vy0 & vx0)) w00 = 0.0f;
    if (!(vy0 & vx1)) w01 = 0.0f;
    if (!(vy1 & vx0)) w10 = 0.0f;
    if (!(vy1 & vx1)) w11 = 0.0f;
    int cx0 = min(max(ix0, 0), WW-1), cx1 = min(max(ix1, 0), WW-1);
    int cy0 = min(max(iy0, 0), HH-1), cy1 = min(max(iy1, 0), HH-1);
    int b00 = (cy0*WW + cx0)*16, b01 = (cy0*WW + cx1)*16;
    int b10 = (cy1*WW + cx0)*16, b11 = (cy1*WW + cx1)*16;

    // this lane's 16 channels: cg = q*4 + cgi
    float4 fc4[4];
    #pragma unroll
    for (int cgi = 0; cgi < 4; cgi++) {
      int cb = q*4 + cgi;
      float4 t00 = Fv[b00 + cb], t01 = Fv[b01 + cb];
      float4 t10 = Fv[b10 + cb], t11 = Fv[b11 + cb];
      float4 f;
      f.x = fmaf(w00,t00.x, fmaf(w01,t01.x, fmaf(w10,t10.x, w11*t11.x)));
      f.y = fmaf(w00,t00.y, fmaf(w01,t01.y, fmaf(w10,t10.y, w11*t11.y)));
      f.z = fmaf(w00,t00.z, fmaf(w01,t01.z, fmaf(w10,t10.z, w11*t11.z)));
      f.w = fmaf(w00,t00.w, fmaf(w01,t01.w, fmaf(w10,t10.w, w11*t11.w)));
      fc4[cgi] = f;
    }
    // partial mid over this lane's 16 channels
    const float4* CWv = (const float4*)(ws + O_CWC + cls*512);
    float mid[8];
    #pragma unroll
    for (int k = 0; k < 8; k++) {
      float mm = 0.0f;
      #pragma unroll
      for (int cgi = 0; cgi < 4; cgi++) {
        float4 w = CWv[k*16 + q*4 + cgi];
        mm = fmaf(w.x, fc4[cgi].x, fmaf(w.y, fc4[cgi].y, fmaf(w.z, fc4[cgi].z, fmaf(w.w, fc4[cgi].w, mm))));
      }
      mid[k] = mm;
    }
    // butterfly-reduce mid over the 4 q-lanes (same s)
    #pragma unroll
    for (int k = 0; k < 8; k++) {
      mid[k] += __shfl_xor(mid[k], 1);
      mid[k] += __shfl_xor(mid[k], 2);
    }
    // phase 2 for this lane's 16 channels
    const float4* WEv = (const float4*)(ws + O_CWE + cls*512);
    #pragma unroll
    for (int cgi = 0; cgi < 4; cgi++) {
      float vv[4];
      #pragma unroll
      for (int cc = 0; cc < 4; cc++) {
        int c_ = (q*4 + cgi)*4 + cc;
        float4 wa = WEv[c_*2], wb = WEv[c_*2 + 1];
        float o_ = fmaf(wa.x,mid[0], fmaf(wa.y,mid[1], fmaf(wa.z,mid[2], wa.w*mid[3])));
        o_ = fmaf(wb.x,mid[4], fmaf(wb.y,mid[5], fmaf(wb.z,mid[6], fmaf(wb.w,mid[7], o_))));
        float fcomp = (cc == 0) ? fc4[cgi].x : (cc == 1) ? fc4[cgi].y : (cc == 2) ? fc4[cgi].z : fc4[cgi].w;
        vv[cc] = o_ + fcomp;
      }
      shd[(q*8 + 2*cgi    )*181 + s] = pk2(vv[0], vv[1]);
      shd[(q*8 + 2*cgi + 1)*181 + s] = pk2(vv[2], vv[3]);
    }
  }
  __syncthreads();

  // tail conv 64->3 over 8x16 tile, channels split across two thread-halves
  int half = t >> 7, pi = t & 127;
  int tx = pi & 15, ty = pi >> 4;
  int slots[9];
  #pragma unroll
  for (int dy = 0; dy < 3; dy++)
    #pragma unroll
    for (int dx = 0; dx < 3; dx++)
      slots[dy*3 + dx] = sof[(ty + dy)*18 + (tx + dx)];
  const float* TWP = ws + O_TWP;
  float a0, a1, a2;
  if (half == 0) { a0 = ws[O_TB + 0]; a1 = ws[O_TB + 1]; a2 = ws[O_TB + 2]; }
  else           { a0 = 0.0f; a1 = 0.0f; a2 = 0.0f; }
  for (int cpl = 0; cpl < 16; cpl++) {
    int cp = half*16 + cpl;
    #pragma unroll
    for (int j = 0; j < 9; j++) {
      unsigned int d = shd[cp*181 + slots[j]];
      float lo = asf(d << 16);
      float hi = asf(d & 0xffff0000u);
      float wl0 = TWP[(0*9 + j)*64 + 2*cp], wh0 = TWP[(0*9 + j)*64 + 2*cp + 1];
      float wl1 = TWP[(1*9 + j)*64 + 2*cp], wh1 = TWP[(1*9 + j)*64 + 2*cp + 1];
      float wl2 = TWP[(2*9 + j)*64 + 2*cp], wh2 = TWP[(2*9 + j)*64 + 2*cp + 1];
      a0 = fmaf(wl0, lo, fmaf(wh0, hi, a0));
      a1 = fmaf(wl1, lo, fmaf(wh1, hi, a1));
      a2 = fmaf(wl2, lo, fmaf(wh2, hi, a2));
    }
  }
  if (half == 1) {
    spart[pi*3 + 0] = a0; spart[pi*3 + 1] = a1; spart[pi*3 + 2] = a2;
  }
  __syncthreads();
  if (half == 0) {
    a0 += spart[pi*3 + 0]; a1 += spart[pi*3 + 1]; a2 += spart[pi*3 + 2];
    int p = (ty0 + ty)*WSZ + (tx0 + tx);
    pred[p*3 + 0] = a0;
    pred[p*3 + 1] = a1;
    pred[p*3 + 2] = a2;
  }
}

// ---- 5. query gather ----
__global__ __launch_bounds__(256) void k_gather(const void* __restrict__ coord, const void* __restrict__ cell,
                                                const float* __restrict__ ws, void* __restrict__ outp) {
  const float* pred = ws + O_PRED;
  bool f32m = ws[O_FLAG] > 0.5f;
  int q = blockIdx.x*256 + threadIdx.x;
  float cy = rdin(coord, q*2 + 0, f32m);
  float cx = rdin(coord, q*2 + 1, f32m);
  float ly = rdin(cell, q*2 + 0, f32m);
  float lx = rdin(cell, q*2 + 1, f32m);
  float gyq = fminf(fmaxf(cy - ly*0.5f + 1e-6f, -1.0f + 1e-6f), 1.0f - 1e-6f);
  float gxq = fminf(fmaxf(cx - lx*0.5f + 1e-6f, -1.0f + 1e-6f), 1.0f - 1e-6f);
  int xi = (int)rintf((gxq + 1.0f)*0.5f*511.0f);
  int yi = (int)rintf((gyq + 1.0f)*0.5f*511.0f);
  xi = min(max(xi, 0), WSZ-1);
  yi = min(max(yi, 0), HS-1);
  int pp = yi*WSZ + xi;
  float v0 = pred[pp*3 + 0], v1 = pred[pp*3 + 1], v2 = pred[pp*3 + 2];
  if (f32m) {
    float* o = (float*)outp;
    o[q*3 + 0] = v0; o[q*3 + 1] = v1; o[q*3 + 2] = v2;
  } else {
    bf16* o = (bf16*)outp;
    o[q*3 + 0] = __float2bfloat16(v0);
    o[q*3 + 1] = __float2bfloat16(v1);
    o[q*3 + 2] = __float2bfloat16(v2);
  }
}

extern "C" void kernel_launch(void* const* d_in, const int* in_sizes, int n_in,
                              void* d_out, int out_size, void* d_ws, size_t ws_size,
                              hipStream_t stream) {
  const void* inp   = d_in[0];
  const void* coord = d_in[1];
  const void* cell  = d_in[2];
  const void* encw  = d_in[3];
  const void* encb  = d_in[4];
  const void* w1    = d_in[5];
  const void* b1    = d_in[6];
  const void* w2    = d_in[7];
  const void* b2    = d_in[8];
  const void* rw    = d_in[9];
  const void* rb    = d_in[10];
  const void* ow    = d_in[11];
  const void* ob    = d_in[12];
  const void* tw    = d_in[13];
  const void* tb    = d_in[14];
  const void* wc    = d_in[15];
  const void* we    = d_in[16];

  float* wsf  = (float*)d_ws;
  float* feat = wsf + O_FEAT;
  float* pred = wsf + O_PRED;

  k_sniff<<<1, 64, 0, stream>>>(inp, wsf);
  k_convert<<<192, 256, 0, stream>>>(inp, encw, encb, w1, b1, w2, b2, rw, rb, ow, ob, tw, tb, wc, we, wsf);
  k_classcombine<<<16, 64, 0, stream>>>(wsf);
  k_enc<<<256, 64, 0, stream>>>(wsf, feat);
  k_maintail<<<2048, 256, 0, stream>>>(wsf, pred);
  k_gather<<<1024, 256, 0, stream>>>(coord, cell, wsf, d_out);
}

// Round 5
// 376.828 us; speedup vs baseline: 1.0447x; 1.0447x over previous
//
#include <hip/hip_runtime.h>
#include <hip/hip_bf16.h>

typedef __hip_bfloat16 bf16;

__device__ __forceinline__ float bf2f(bf16 h) { return __bfloat162float(h); }
__device__ __forceinline__ bf16 us2bf(unsigned short u) {
  union { unsigned short s; bf16 h; } v; v.s = u; return v.h;
}
__device__ __forceinline__ unsigned int pk2(float a, float b) {
  union { bf16 h; unsigned short u; } ua, ub;
  ua.h = __float2bfloat16(a); ub.h = __float2bfloat16(b);
  return ((unsigned int)ub.u << 16) | (unsigned int)ua.u;
}
__device__ __forceinline__ float asf(unsigned int u) {
  union { unsigned int u; float f; } v; v.u = u; return v.f;
}

#define HH 128
#define WW 128
#define HS 512
#define WSZ 512
#define NC 64
#define QN (HS*WSZ)

// ---- ws float-offset layout ----
#define O_INP    0        // 49152
#define O_ENCW   49152    // 1728
#define O_ENCB   50880    // 64
#define O_W1     50944    // 256
#define O_B1     51200    // 64
#define O_W2     51264    // 4096
#define O_B2     55360    // 64
#define O_RW     55424    // 256
#define O_RB     55680    // 4
#define O_OW     55684    // 128
#define O_OB     55812    // 2
#define O_TW     55814    // 1728
#define O_TB     57542    // 3
#define O_WC     57545    // 2048
#define O_WE     59593    // 2048
#define O_OFFTAB 61696    // 32
#define O_RTAB   61728    // 64
#define O_FLAG   61792    // 1
#define O_CWC    61824    // 16*512 [cls][k][c]
#define O_CWE    70016    // 16*512 [cls][c][k]
#define O_TWP    78208    // 1728 [o][j][c]
#define O_FEAT   81920    // 16384*64 f32 HWC
#define O_PRED   1130496  // 262144*3 f32 HWC

// class-sorted halo decode prefix for 10x18 halo (classes by ((p+3)&3))
// ny = [3,2,2,3] (a), nx = [5,4,4,5] (b); counts = ny*nx
__constant__ int PREF2[16] = {0,15,27,39,54,64,72,80,90,100,108,116,126,141,153,165};

__device__ __forceinline__ float rdin(const void* p, int i, bool f32m) {
  return f32m ? ((const float*)p)[i] : bf2f(((const bf16*)p)[i]);
}

// ---- 0. dtype sniff ----
__global__ void k_sniff(const void* __restrict__ inp, float* __restrict__ ws) {
  int o = threadIdx.x;
  unsigned short u = ((const unsigned short*)inp)[2*o];
  float v = bf2f(us2bf(u));
  bool bf_ok = (v == v) && (fabsf(v) < 64.0f);
  unsigned long long m = __ballot(bf_ok);
  if (o == 0) ws[O_FLAG] = (__popcll(m) >= 48) ? 0.0f : 1.0f;
}

// ---- 1. convert inputs/weights to f32 ----
__global__ __launch_bounds__(256) void k_convert(
    const void* __restrict__ inp, const void* __restrict__ encw, const void* __restrict__ encb,
    const void* __restrict__ w1, const void* __restrict__ b1,
    const void* __restrict__ w2, const void* __restrict__ b2,
    const void* __restrict__ rw, const void* __restrict__ rb,
    const void* __restrict__ ow, const void* __restrict__ ob,
    const void* __restrict__ tw, const void* __restrict__ tb,
    const void* __restrict__ wc, const void* __restrict__ we,
    float* __restrict__ ws) {
  bool f32m = ws[O_FLAG] > 0.5f;
  int i = blockIdx.x*256 + threadIdx.x;
  if (i < 49152) ws[O_INP + i] = rdin(inp, i, f32m);
  if (i < 1728) { ws[O_ENCW + i] = rdin(encw, i, f32m); ws[O_TW + i] = rdin(tw, i, f32m); }
  if (i < 64)   { ws[O_ENCB+i] = rdin(encb,i,f32m); ws[O_B1+i] = rdin(b1,i,f32m); ws[O_B2+i] = rdin(b2,i,f32m); }
  if (i < 256)  { ws[O_W1+i] = rdin(w1,i,f32m); ws[O_RW+i] = rdin(rw,i,f32m); }
  if (i < 4096) ws[O_W2+i] = rdin(w2,i,f32m);
  if (i < 4)    ws[O_RB+i] = rdin(rb,i,f32m);
  if (i < 128)  ws[O_OW+i] = rdin(ow,i,f32m);
  if (i < 2)    ws[O_OB+i] = rdin(ob,i,f32m);
  if (i < 3)    ws[O_TB+i] = rdin(tb,i,f32m);
  if (i < 2048) { ws[O_WC+i] = rdin(wc,i,f32m); ws[O_WE+i] = rdin(we,i,f32m); }
}

// ---- 2. per-class MLP -> off, r; fold into combined weights; transpose tail weights ----
__global__ __launch_bounds__(64) void k_classcombine(float* __restrict__ ws) {
  __shared__ float sh1[64];
  __shared__ float sh2[64];
  __shared__ float shr[4];
  int cls = blockIdx.x;
  int o = threadIdx.x;
  float m = (float)(cls >> 2), n = (float)(cls & 3);
  float ch = (m + 0.5f)*0.25f - 0.5f;
  float cw = (n + 0.5f)*0.25f - 0.5f;
  const float* W1 = ws + O_W1; const float* B1 = ws + O_B1;
  const float* W2 = ws + O_W2; const float* B2 = ws + O_B2;
  float s = W1[o*4+0]*0.25f + W1[o*4+1]*0.25f + W1[o*4+2]*ch + W1[o*4+3]*cw + B1[o];
  sh1[o] = fmaxf(s, 0.0f);
  __syncthreads();
  float s2 = B2[o];
  for (int i = 0; i < 64; i++) s2 = fmaf(W2[o*64+i], sh1[i], s2);
  sh2[o] = fmaxf(s2, 0.0f);
  __syncthreads();
  if (o < 2) {
    const float* OW = ws + O_OW;
    float a = ws[O_OB + o];
    for (int i = 0; i < 64; i++) a = fmaf(OW[o*64+i], sh2[i], a);
    ws[O_OFFTAB + cls*2 + o] = a;
  } else if (o < 6) {
    int e = o - 2;
    const float* RW = ws + O_RW;
    float a = ws[O_RB + e];
    for (int i = 0; i < 64; i++) a = fmaf(RW[e*64+i], sh2[i], a);
    shr[e] = 1.0f / (1.0f + expf(-a));
    ws[O_RTAB + cls*4 + e] = shr[e];
  }
  __syncthreads();
  float r0 = shr[0], r1 = shr[1], r2 = shr[2], r3 = shr[3];
  const float* WC = ws + O_WC;
  const float* WE = ws + O_WE;
  for (int idx = o; idx < 512; idx += 64) {
    float a =       r0 * WC[0*512 + idx];
    a = fmaf(r1, WC[1*512 + idx], a);
    a = fmaf(r2, WC[2*512 + idx], a);
    a = fmaf(r3, WC[3*512 + idx], a);
    ws[O_CWC + cls*512 + idx] = a;
    float b =       r0 * WE[0*512 + idx];
    b = fmaf(r1, WE[1*512 + idx], b);
    b = fmaf(r2, WE[2*512 + idx], b);
    b = fmaf(r3, WE[3*512 + idx], b);
    ws[O_CWE + cls*512 + idx] = b;
  }
  if (cls == 0) {
    for (int idx = o; idx < 1728; idx += 64) {
      int oo = idx / 576;
      int rem = idx - oo*576;
      int jj = rem >> 6;
      int c = rem & 63;
      ws[O_TWP + idx] = ws[O_TW + (oo*64 + c)*9 + jj];
    }
  }
}

// ---- 3. encoder conv 3->64 -> feat HWC f32 (256 blocks x 64 thr) ----
__global__ __launch_bounds__(64) void k_enc(const float* __restrict__ ws, float* __restrict__ feat) {
  int px = blockIdx.x*64 + threadIdx.x;     // 0..16383
  int x = px & 127, y = px >> 7;
  const float* I = ws + O_INP;
  float tp[27];
  #pragma unroll
  for (int ic = 0; ic < 3; ic++) {
    #pragma unroll
    for (int dy = 0; dy < 3; dy++) {
      int yy = y + dy - 1;
      #pragma unroll
      for (int dx = 0; dx < 3; dx++) {
        int xx = x + dx - 1;
        bool ok = (yy >= 0) & (yy < 128) & (xx >= 0) & (xx < 128);
        tp[ic*9 + dy*3 + dx] = ok ? I[ic*16384 + yy*128 + xx] : 0.0f;
      }
    }
  }
  const float* EW = ws + O_ENCW;
  float4* out = (float4*)(feat + (size_t)px*64);
  for (int og = 0; og < 16; og++) {
    float a[4];
    #pragma unroll
    for (int oo = 0; oo < 4; oo++) {
      float acc = ws[O_ENCB + og*4 + oo];
      #pragma unroll
      for (int kk = 0; kk < 27; kk++) acc = fmaf(EW[(og*4 + oo)*27 + kk], tp[kk], acc);
      a[oo] = acc;
    }
    out[og] = make_float4(a[0], a[1], a[2], a[3]);
  }
}

// ---- 4. fused main+tail: tile 8x16, halo 10x18, 4-lane coop phase A ----
// launch_bounds(256,4): VGPR cap 128 (round-4's (256,6) forced 40 VGPRs -> scratch
// spills, 30ms outlier dispatch, VALUBusy 15%). LDS (25KB) caps residency at 6 blocks/CU.
__global__ __launch_bounds__(256, 4) void k_maintail(const float* __restrict__ ws, float* __restrict__ pred) {
  __shared__ unsigned int shd[32*181];     // [cp][slot] packed bf16 pairs, 23168 B
  __shared__ unsigned short sof[192];      // pos -> slot
  __shared__ float spart[384];             // tail upper-half partials
  int blk = blockIdx.x;                    // 0..2047
  int xcd = blk & 7, local = blk >> 3;     // XCD-banded tile mapping for L2 locality
  int ty0 = (xcd*8 + (local >> 5)) * 8;
  int tx0 = (local & 31) * 16;
  int t = threadIdx.x;
  int q = t & 3;
  const float4* Fv = (const float4*)(ws + O_FEAT);

  for (int base = 0; base < 192; base += 64) {
    int s = base + (t >> 2);
    if (s >= 180) continue;
    int cls = 0;
    #pragma unroll
    for (int i = 1; i < 16; i++) cls += (s >= PREF2[i]) ? 1 : 0;
    int j = s - PREF2[cls];
    int a = cls >> 2, bb = cls & 3;
    int nx = ((bb == 0) | (bb == 3)) ? 5 : 4;
    int jy = (nx == 4) ? (j >> 2) : ((j*13) >> 6);
    int jx = j - jy*nx;
    int py = ((a + 1) & 3) + 4*jy;
    int px = ((bb + 1) & 3) + 4*jx;
    int pos = py*18 + px;
    if (q == 0) sof[pos] = (unsigned short)s;
    int gy = ty0 - 1 + py, gx = tx0 - 1 + px;
    if ((gy < 0) | (gy >= HS) | (gx < 0) | (gx >= WSZ)) {
      #pragma unroll
      for (int w = 0; w < 8; w++) shd[(q*8 + w)*181 + s] = 0u;
      continue;
    }
    float off0 = ws[O_OFFTAB + cls*2 + 0];
    float off1 = ws[O_OFFTAB + cls*2 + 1];
    float gxf = (((float)gx + 0.5f)*0.25f - 0.5f)*(2.0f/127.0f) - 1.0f + off0*(2.0f/127.0f);
    float gyf = (((float)gy + 0.5f)*0.25f - 0.5f)*(2.0f/127.0f) - 1.0f + off1*(2.0f/127.0f);
    float sx = (gxf + 1.0f)*0.5f*127.0f;
    float sy = (gyf + 1.0f)*0.5f*127.0f;
    float x0f = floorf(sx), y0f = floorf(sy);
    float fx = sx - x0f, fy = sy - y0f;
    int ix0 = (int)x0f, iy0 = (int)y0f;
    int ix1 = ix0 + 1, iy1 = iy0 + 1;
    float wx0 = 1.0f - fx, wy0 = 1.0f - fy;
    float w00 = wy0*wx0, w01 = wy0*fx, w10 = fy*wx0, w11 = fy*fx;
    bool vx0 = (ix0 >= 0) & (ix0 < WW), vx1 = (ix1 >= 0) & (ix1 < WW);
    bool vy0 = (iy0 >= 0) & (iy0 < HH), vy1 = (iy1 >= 0) & (iy1 < HH);
    if (!(vy0 & vx0)) w00 = 0.0f;
    if (!(vy0 & vx1)) w01 = 0.0f;
    if (!(vy1 & vx0)) w10 = 0.0f;
    if (!(vy1 & vx1)) w11 = 0.0f;
    int cx0 = min(max(ix0, 0), WW-1), cx1 = min(max(ix1, 0), WW-1);
    int cy0 = min(max(iy0, 0), HH-1), cy1 = min(max(iy1, 0), HH-1);
    int b00 = (cy0*WW + cx0)*16, b01 = (cy0*WW + cx1)*16;
    int b10 = (cy1*WW + cx0)*16, b11 = (cy1*WW + cx1)*16;

    // this lane's 16 channels: cg = q*4 + cgi
    float4 fc4[4];
    #pragma unroll
    for (int cgi = 0; cgi < 4; cgi++) {
      int cb = q*4 + cgi;
      float4 t00 = Fv[b00 + cb], t01 = Fv[b01 + cb];
      float4 t10 = Fv[b10 + cb], t11 = Fv[b11 + cb];
      float4 f;
      f.x = fmaf(w00,t00.x, fmaf(w01,t01.x, fmaf(w10,t10.x, w11*t11.x)));
      f.y = fmaf(w00,t00.y, fmaf(w01,t01.y, fmaf(w10,t10.y, w11*t11.y)));
      f.z = fmaf(w00,t00.z, fmaf(w01,t01.z, fmaf(w10,t10.z, w11*t11.z)));
      f.w = fmaf(w00,t00.w, fmaf(w01,t01.w, fmaf(w10,t10.w, w11*t11.w)));
      fc4[cgi] = f;
    }
    // partial mid over this lane's 16 channels
    const float4* CWv = (const float4*)(ws + O_CWC + cls*512);
    float mid[8];
    #pragma unroll
    for (int k = 0; k < 8; k++) {
      float mm = 0.0f;
      #pragma unroll
      for (int cgi = 0; cgi < 4; cgi++) {
        float4 w = CWv[k*16 + q*4 + cgi];
        mm = fmaf(w.x, fc4[cgi].x, fmaf(w.y, fc4[cgi].y, fmaf(w.z, fc4[cgi].z, fmaf(w.w, fc4[cgi].w, mm))));
      }
      mid[k] = mm;
    }
    // butterfly-reduce mid over the 4 q-lanes (same s)
    #pragma unroll
    for (int k = 0; k < 8; k++) {
      mid[k] += __shfl_xor(mid[k], 1);
      mid[k] += __shfl_xor(mid[k], 2);
    }
    // phase 2 for this lane's 16 channels
    const float4* WEv = (const float4*)(ws + O_CWE + cls*512);
    #pragma unroll
    for (int cgi = 0; cgi < 4; cgi++) {
      float vv[4];
      #pragma unroll
      for (int cc = 0; cc < 4; cc++) {
        int c_ = (q*4 + cgi)*4 + cc;
        float4 wa = WEv[c_*2], wb = WEv[c_*2 + 1];
        float o_ = fmaf(wa.x,mid[0], fmaf(wa.y,mid[1], fmaf(wa.z,mid[2], wa.w*mid[3])));
        o_ = fmaf(wb.x,mid[4], fmaf(wb.y,mid[5], fmaf(wb.z,mid[6], fmaf(wb.w,mid[7], o_))));
        float fcomp = (cc == 0) ? fc4[cgi].x : (cc == 1) ? fc4[cgi].y : (cc == 2) ? fc4[cgi].z : fc4[cgi].w;
        vv[cc] = o_ + fcomp;
      }
      shd[(q*8 + 2*cgi    )*181 + s] = pk2(vv[0], vv[1]);
      shd[(q*8 + 2*cgi + 1)*181 + s] = pk2(vv[2], vv[3]);
    }
  }
  __syncthreads();

  // tail conv 64->3 over 8x16 tile, channels split across two thread-halves
  int half = t >> 7, pi = t & 127;
  int tx = pi & 15, ty = pi >> 4;
  int slots[9];
  #pragma unroll
  for (int dy = 0; dy < 3; dy++)
    #pragma unroll
    for (int dx = 0; dx < 3; dx++)
      slots[dy*3 + dx] = sof[(ty + dy)*18 + (tx + dx)];
  const float* TWP = ws + O_TWP;
  float a0, a1, a2;
  if (half == 0) { a0 = ws[O_TB + 0]; a1 = ws[O_TB + 1]; a2 = ws[O_TB + 2]; }
  else           { a0 = 0.0f; a1 = 0.0f; a2 = 0.0f; }
  for (int cpl = 0; cpl < 16; cpl++) {
    int cp = half*16 + cpl;
    #pragma unroll
    for (int j = 0; j < 9; j++) {
      unsigned int d = shd[cp*181 + slots[j]];
      float lo = asf(d << 16);
      float hi = asf(d & 0xffff0000u);
      float wl0 = TWP[(0*9 + j)*64 + 2*cp], wh0 = TWP[(0*9 + j)*64 + 2*cp + 1];
      float wl1 = TWP[(1*9 + j)*64 + 2*cp], wh1 = TWP[(1*9 + j)*64 + 2*cp + 1];
      float wl2 = TWP[(2*9 + j)*64 + 2*cp], wh2 = TWP[(2*9 + j)*64 + 2*cp + 1];
      a0 = fmaf(wl0, lo, fmaf(wh0, hi, a0));
      a1 = fmaf(wl1, lo, fmaf(wh1, hi, a1));
      a2 = fmaf(wl2, lo, fmaf(wh2, hi, a2));
    }
  }
  if (half == 1) {
    spart[pi*3 + 0] = a0; spart[pi*3 + 1] = a1; spart[pi*3 + 2] = a2;
  }
  __syncthreads();
  if (half == 0) {
    a0 += spart[pi*3 + 0]; a1 += spart[pi*3 + 1]; a2 += spart[pi*3 + 2];
    int p = (ty0 + ty)*WSZ + (tx0 + tx);
    pred[p*3 + 0] = a0;
    pred[p*3 + 1] = a1;
    pred[p*3 + 2] = a2;
  }
}

// ---- 5. query gather ----
__global__ __launch_bounds__(256) void k_gather(const void* __restrict__ coord, const void* __restrict__ cell,
                                                const float* __restrict__ ws, void* __restrict__ outp) {
  const float* pred = ws + O_PRED;
  bool f32m = ws[O_FLAG] > 0.5f;
  int q = blockIdx.x*256 + threadIdx.x;
  float cy = rdin(coord, q*2 + 0, f32m);
  float cx = rdin(coord, q*2 + 1, f32m);
  float ly = rdin(cell, q*2 + 0, f32m);
  float lx = rdin(cell, q*2 + 1, f32m);
  float gyq = fminf(fmaxf(cy - ly*0.5f + 1e-6f, -1.0f + 1e-6f), 1.0f - 1e-6f);
  float gxq = fminf(fmaxf(cx - lx*0.5f + 1e-6f, -1.0f + 1e-6f), 1.0f - 1e-6f);
  int xi = (int)rintf((gxq + 1.0f)*0.5f*511.0f);
  int yi = (int)rintf((gyq + 1.0f)*0.5f*511.0f);
  xi = min(max(xi, 0), WSZ-1);
  yi = min(max(yi, 0), HS-1);
  int pp = yi*WSZ + xi;
  float v0 = pred[pp*3 + 0], v1 = pred[pp*3 + 1], v2 = pred[pp*3 + 2];
  if (f32m) {
    float* o = (float*)outp;
    o[q*3 + 0] = v0; o[q*3 + 1] = v1; o[q*3 + 2] = v2;
  } else {
    bf16* o = (bf16*)outp;
    o[q*3 + 0] = __float2bfloat16(v0);
    o[q*3 + 1] = __float2bfloat16(v1);
    o[q*3 + 2] = __float2bfloat16(v2);
  }
}

extern "C" void kernel_launch(void* const* d_in, const int* in_sizes, int n_in,
                              void* d_out, int out_size, void* d_ws, size_t ws_size,
                              hipStream_t stream) {
  const void* inp   = d_in[0];
  const void* coord = d_in[1];
  const void* cell  = d_in[2];
  const void* encw  = d_in[3];
  const void* encb  = d_in[4];
  const void* w1    = d_in[5];
  const void* b1    = d_in[6];
  const void* w2    = d_in[7];
  const void* b2    = d_in[8];
  const void* rw    = d_in[9];
  const void* rb    = d_in[10];
  const void* ow    = d_in[11];
  const void* ob    = d_in[12];
  const void* tw    = d_in[13];
  const void* tb    = d_in[14];
  const void* wc    = d_in[15];
  const void* we    = d_in[16];

  float* wsf  = (float*)d_ws;
  float* feat = wsf + O_FEAT;
  float* pred = wsf + O_PRED;

  k_sniff<<<1, 64, 0, stream>>>(inp, wsf);
  k_convert<<<192, 256, 0, stream>>>(inp, encw, encb, w1, b1, w2, b2, rw, rb, ow, ob, tw, tb, wc, we, wsf);
  k_classcombine<<<16, 64, 0, stream>>>(wsf);
  k_enc<<<256, 64, 0, stream>>>(wsf, feat);
  k_maintail<<<2048, 256, 0, stream>>>(wsf, pred);
  k_gather<<<1024, 256, 0, stream>>>(coord, cell, wsf, d_out);
}

// Round 7
// 265.796 us; speedup vs baseline: 1.4810x; 1.4177x over previous
//
#include <hip/hip_runtime.h>
#include <hip/hip_bf16.h>

typedef __hip_bfloat16 bf16;
typedef __fp16 h2 __attribute__((ext_vector_type(2)));   // matches V2h of amdgcn builtins

__device__ __forceinline__ float bf2f(bf16 h) { return __bfloat162float(h); }
__device__ __forceinline__ bf16 us2bf(unsigned short u){ union{unsigned short s; bf16 h;}v; v.s=u; return v.h; }
__device__ __forceinline__ float asf(unsigned u){ union{unsigned u; float f;}v; v.u=u; return v.f; }
__device__ __forceinline__ h2 uh(unsigned u){ union{unsigned u; h2 h;}v; v.u=u; return v.h; }
__device__ __forceinline__ unsigned pkh(float a, float b){ union{h2 h; unsigned u;}v; v.h=__builtin_amdgcn_cvt_pkrtz(a,b); return v.u; }
#define FDOT2(va,vb,acc) __builtin_amdgcn_fdot2((va),(vb),(acc),false)

#define HH 128
#define WW 128
#define HS 512
#define WSZ 512
#define QN (HS*WSZ)

// ---- ws dword-offset layout (~7.4 MB) ----
#define O_OFFTAB 0        // 32 f32
#define O_TB     32       // 3 f32
#define O_TW2    64       // 864 u32: tail weights f16 pairs [o][j][cpair]
#define O_CWC2   1024     // 4096 u32: f16 pairs [cls][cpair][k]
#define O_W2P    5120     // 1728 u32: f16 pairs [cls][j][o][kpair]
#define O_FEAT   8192     // 1048576 f32 HWC
#define O_PRED   1056768  // 786432 f32 HWC

// class-sorted halo decode prefix for 10x18 halo (classes by ((p+3)&3))
__constant__ int PREF2[16] = {0,15,27,39,54,64,72,80,90,100,108,116,126,141,153,165};

__device__ __forceinline__ float rdin(const void* p, int i, bool f32m) {
  return f32m ? ((const float*)p)[i] : bf2f(((const bf16*)p)[i]);
}
// uniform-index-friendly read (dword load + shift -> scalarizable)
__device__ __forceinline__ float rdw(const void* p, int i, bool f32m) {
  if (f32m) return ((const float*)p)[i];
  unsigned u = ((const unsigned*)p)[i>>1];
  return asf((i&1) ? (u & 0xffff0000u) : (u<<16));
}
// per-wave dtype sniff: true => f32 inputs
__device__ __forceinline__ bool sniff_f32(const void* inp) {
  int lane = threadIdx.x & 63;
  unsigned short u = ((const unsigned short*)inp)[2*lane];
  float v = bf2f(us2bf(u));
  bool ok = (v == v) && (fabsf(v) < 64.0f);
  return __popcll(__ballot(ok)) < 48;
}

// ==== K1: encoder conv + per-class MLP/combined-weights + weight packing ====
__global__ __launch_bounds__(64) void k_prep(
    const void* __restrict__ inp, const void* __restrict__ encw, const void* __restrict__ encb,
    const void* __restrict__ w1, const void* __restrict__ b1,
    const void* __restrict__ w2, const void* __restrict__ b2,
    const void* __restrict__ rw, const void* __restrict__ rb,
    const void* __restrict__ ow, const void* __restrict__ ob,
    const void* __restrict__ tw, const void* __restrict__ tb,
    const void* __restrict__ wc, const void* __restrict__ we,
    float* __restrict__ ws) {
  __shared__ float sh1[64];
  __shared__ float sh2[64];
  __shared__ float shr[4];
  __shared__ float shcwe[512];
  bool f32m = sniff_f32(inp);
  int b = blockIdx.x, t = threadIdx.x;

  if (b < 256) {
    // ---- encoder conv 3->64, 3x3 pad1 -> feat HWC f32 ----
    int px = b*64 + t;
    int x = px & 127, y = px >> 7;
    float tp[27];
    #pragma unroll
    for (int ic = 0; ic < 3; ic++)
      #pragma unroll
      for (int dy = 0; dy < 3; dy++) {
        int yy = y + dy - 1;
        #pragma unroll
        for (int dx = 0; dx < 3; dx++) {
          int xx = x + dx - 1;
          bool ok = (yy >= 0) & (yy < 128) & (xx >= 0) & (xx < 128);
          tp[ic*9 + dy*3 + dx] = ok ? rdin(inp, ic*16384 + yy*128 + xx, f32m) : 0.0f;
        }
      }
    float4* out = (float4*)(ws + O_FEAT + (size_t)px*64);
    for (int og = 0; og < 16; og++) {
      float a[4];
      #pragma unroll
      for (int oo = 0; oo < 4; oo++) {
        float acc = rdw(encb, og*4 + oo, f32m);
        #pragma unroll
        for (int kk = 0; kk < 27; kk++)
          acc = fmaf(rdw(encw, (og*4 + oo)*27 + kk, f32m), tp[kk], acc);
        a[oo] = acc;
      }
      out[og] = make_float4(a[0], a[1], a[2], a[3]);
    }
  } else if (b < 272) {
    // ---- per-class MLP -> off, r; fold into CWC2 / W2P ----
    int cls = b - 256, o = t;
    float mcls = (float)(cls >> 2), ncls = (float)(cls & 3);
    float chv = (mcls + 0.5f)*0.25f - 0.5f;
    float cwv = (ncls + 0.5f)*0.25f - 0.5f;
    float s1 = rdw(w1,o*4+0,f32m)*0.25f + rdw(w1,o*4+1,f32m)*0.25f
             + rdw(w1,o*4+2,f32m)*chv + rdw(w1,o*4+3,f32m)*cwv + rdw(b1,o,f32m);
    sh1[o] = fmaxf(s1, 0.0f);
    __syncthreads();
    float s2 = rdw(b2,o,f32m);
    for (int i = 0; i < 64; i++) s2 = fmaf(rdw(w2,o*64+i,f32m), sh1[i], s2);
    sh2[o] = fmaxf(s2, 0.0f);
    __syncthreads();
    if (o < 2) {
      float a = rdw(ob,o,f32m);
      for (int i = 0; i < 64; i++) a = fmaf(rdw(ow,o*64+i,f32m), sh2[i], a);
      ws[O_OFFTAB + cls*2 + o] = a;
    } else if (o < 6) {
      int e = o - 2;
      float a = rdw(rb,e,f32m);
      for (int i = 0; i < 64; i++) a = fmaf(rdw(rw,e*64+i,f32m), sh2[i], a);
      shr[e] = 1.0f / (1.0f + expf(-a));
    }
    __syncthreads();
    float r0 = shr[0], r1 = shr[1], r2 = shr[2], r3 = shr[3];
    // CWE (f32, LDS only): cwe[c*8+k] = sum_e r_e we[e][c][k]
    for (int idx = o; idx < 512; idx += 64) {
      float a =       r0 * rdw(we,        idx, f32m);
      a = fmaf(r1, rdw(we,  512 + idx, f32m), a);
      a = fmaf(r2, rdw(we, 1024 + idx, f32m), a);
      a = fmaf(r3, rdw(we, 1536 + idx, f32m), a);
      shcwe[idx] = a;
    }
    // CWC2 [cls][cp][k] f16 pairs over channel pair
    unsigned* wcw = (unsigned*)(ws + O_CWC2) + cls*256;
    for (int idx = o; idx < 256; idx += 64) {
      int cp = idx >> 3, k = idx & 7;
      float lo =       r0 * rdw(wc,        k*64 + 2*cp, f32m);
      lo = fmaf(r1, rdw(wc,  512 + k*64 + 2*cp, f32m), lo);
      lo = fmaf(r2, rdw(wc, 1024 + k*64 + 2*cp, f32m), lo);
      lo = fmaf(r3, rdw(wc, 1536 + k*64 + 2*cp, f32m), lo);
      float hi =       r0 * rdw(wc,        k*64 + 2*cp + 1, f32m);
      hi = fmaf(r1, rdw(wc,  512 + k*64 + 2*cp + 1, f32m), hi);
      hi = fmaf(r2, rdw(wc, 1024 + k*64 + 2*cp + 1, f32m), hi);
      hi = fmaf(r3, rdw(wc, 1536 + k*64 + 2*cp + 1, f32m), hi);
      wcw[idx] = pkh(lo, hi);
    }
    __syncthreads();   // shcwe ready
    // W2P [cls][j][o][kpair]: W2[o][k][j] = sum_c tw[o][c][j] * cwe[c][k]
    unsigned* wpp = (unsigned*)(ws + O_W2P);
    for (int idx = o; idx < 108; idx += 64) {
      int j = idx / 12, rem = idx - j*12, o2 = rem >> 2, kp = rem & 3;
      float alo = 0.0f, ahi = 0.0f;
      for (int c = 0; c < 64; c++) {
        float tv = rdw(tw, (o2*64 + c)*9 + j, f32m);
        alo = fmaf(tv, shcwe[c*8 + 2*kp],     alo);
        ahi = fmaf(tv, shcwe[c*8 + 2*kp + 1], ahi);
      }
      wpp[(cls*9 + j)*12 + o2*4 + kp] = pkh(alo, ahi);
    }
  } else {
    // ---- misc: pack tail weights TW2 [o][j][cpair], TB ----
    for (int idx = t; idx < 864; idx += 64) {
      int o2 = idx / 288, rem = idx - o2*288, j = rem >> 5, cp = rem & 31;
      unsigned d = pkh(rdw(tw, (o2*64 + 2*cp    )*9 + j, f32m),
                       rdw(tw, (o2*64 + 2*cp + 1)*9 + j, f32m));
      ((unsigned*)(ws + O_TW2))[idx] = d;
    }
    if (t < 3) ws[O_TB + t] = rdin(tb, t, f32m);
  }
}

// ==== K2: fused main+tail, tile 8x16, halo 10x18, f16/dot2 ====
__global__ __launch_bounds__(256) void k_maintail(const float* __restrict__ ws, float* __restrict__ pred) {
  __shared__ unsigned shf[32*181];               // fc f16 pairs [cpair][slot], 23168 B
  __shared__ __align__(16) unsigned shm4[181*4]; // mid f16 pairs [slot][kpair], 2896 B
  __shared__ unsigned short sof[192];            // pos -> slot
  __shared__ unsigned short scls[192];           // slot -> cls
  __shared__ float spart[128*3];
  int blk = blockIdx.x;                          // 0..2047
  int xcd = blk & 7, local = blk >> 3;           // XCD-banded for L2 locality
  int ty0 = (xcd*8 + (local >> 5)) * 8;
  int tx0 = (local & 31) * 16;
  int t = threadIdx.x;
  const float4* Fv = (const float4*)(ws + O_FEAT);

  if (t < 180) {
    int s = t;
    int cls = 0;
    #pragma unroll
    for (int i = 1; i < 16; i++) cls += (s >= PREF2[i]) ? 1 : 0;
    int j = s - PREF2[cls];
    int a = cls >> 2, bb = cls & 3;
    int nx = ((bb == 0) | (bb == 3)) ? 5 : 4;
    int jy = (nx == 4) ? (j >> 2) : ((j*13) >> 6);
    int jx = j - jy*nx;
    int py = ((a + 1) & 3) + 4*jy;
    int px = ((bb + 1) & 3) + 4*jx;
    int pos = py*18 + px;
    sof[pos] = (unsigned short)s;
    int gy = ty0 - 1 + py, gx = tx0 - 1 + px;
    if ((gy < 0) | (gy >= HS) | (gx < 0) | (gx >= WSZ)) {
      scls[s] = 0;
      #pragma unroll
      for (int cp = 0; cp < 32; cp++) shf[cp*181 + s] = 0u;
      shm4[s*4+0] = 0u; shm4[s*4+1] = 0u; shm4[s*4+2] = 0u; shm4[s*4+3] = 0u;
    } else {
      scls[s] = (unsigned short)cls;
      float off0 = ws[O_OFFTAB + cls*2 + 0];
      float off1 = ws[O_OFFTAB + cls*2 + 1];
      float gxf = (((float)gx + 0.5f)*0.25f - 0.5f)*(2.0f/127.0f) - 1.0f + off0*(2.0f/127.0f);
      float gyf = (((float)gy + 0.5f)*0.25f - 0.5f)*(2.0f/127.0f) - 1.0f + off1*(2.0f/127.0f);
      float sx = (gxf + 1.0f)*0.5f*127.0f;
      float sy = (gyf + 1.0f)*0.5f*127.0f;
      float x0f = floorf(sx), y0f = floorf(sy);
      float fx = sx - x0f, fy = sy - y0f;
      int ix0 = (int)x0f, iy0 = (int)y0f;
      int ix1 = ix0 + 1, iy1 = iy0 + 1;
      float wx0 = 1.0f - fx, wy0 = 1.0f - fy;
      float w00 = wy0*wx0, w01 = wy0*fx, w10 = fy*wx0, w11 = fy*fx;
      bool vx0 = (ix0 >= 0) & (ix0 < WW), vx1 = (ix1 >= 0) & (ix1 < WW);
      bool vy0 = (iy0 >= 0) & (iy0 < HH), vy1 = (iy1 >= 0) & (iy1 < HH);
      if (!(vy0 & vx0)) w00 = 0.0f;
      if (!(vy0 & vx1)) w01 = 0.0f;
      if (!(vy1 & vx0)) w10 = 0.0f;
      if (!(vy1 & vx1)) w11 = 0.0f;
      int cx0 = min(max(ix0, 0), WW-1), cx1 = min(max(ix1, 0), WW-1);
      int cy0 = min(max(iy0, 0), HH-1), cy1 = min(max(iy1, 0), HH-1);
      int b00 = (cy0*WW + cx0)*16, b01 = (cy0*WW + cx1)*16;
      int b10 = (cy1*WW + cx0)*16, b11 = (cy1*WW + cx1)*16;

      const unsigned* CW2 = (const unsigned*)(ws + O_CWC2) + cls*256;
      float mid[8] = {0,0,0,0,0,0,0,0};
      #pragma unroll 2
      for (int cg = 0; cg < 16; cg++) {
        float4 t00 = Fv[b00 + cg], t01 = Fv[b01 + cg];
        float4 t10 = Fv[b10 + cg], t11 = Fv[b11 + cg];
        float4 f;
        f.x = fmaf(w00,t00.x, fmaf(w01,t01.x, fmaf(w10,t10.x, w11*t11.x)));
        f.y = fmaf(w00,t00.y, fmaf(w01,t01.y, fmaf(w10,t10.y, w11*t11.y)));
        f.z = fmaf(w00,t00.z, fmaf(w01,t01.z, fmaf(w10,t10.z, w11*t11.z)));
        f.w = fmaf(w00,t00.w, fmaf(w01,t01.w, fmaf(w10,t10.w, w11*t11.w)));
        unsigned p0 = pkh(f.x, f.y), p1 = pkh(f.z, f.w);
        shf[(2*cg    )*181 + s] = p0;
        shf[(2*cg + 1)*181 + s] = p1;
        const uint4* Ck = (const uint4*)(CW2 + cg*16);
        uint4 c0 = Ck[0], c1 = Ck[1], d0 = Ck[2], d1 = Ck[3];
        h2 h0 = uh(p0), h1 = uh(p1);
        mid[0] = FDOT2(h0, uh(c0.x), mid[0]); mid[0] = FDOT2(h1, uh(d0.x), mid[0]);
        mid[1] = FDOT2(h0, uh(c0.y), mid[1]); mid[1] = FDOT2(h1, uh(d0.y), mid[1]);
        mid[2] = FDOT2(h0, uh(c0.z), mid[2]); mid[2] = FDOT2(h1, uh(d0.z), mid[2]);
        mid[3] = FDOT2(h0, uh(c0.w), mid[3]); mid[3] = FDOT2(h1, uh(d0.w), mid[3]);
        mid[4] = FDOT2(h0, uh(c1.x), mid[4]); mid[4] = FDOT2(h1, uh(d1.x), mid[4]);
        mid[5] = FDOT2(h0, uh(c1.y), mid[5]); mid[5] = FDOT2(h1, uh(d1.y), mid[5]);
        mid[6] = FDOT2(h0, uh(c1.z), mid[6]); mid[6] = FDOT2(h1, uh(d1.z), mid[6]);
        mid[7] = FDOT2(h0, uh(c1.w), mid[7]); mid[7] = FDOT2(h1, uh(d1.w), mid[7]);
      }
      shm4[s*4+0] = pkh(mid[0], mid[1]);
      shm4[s*4+1] = pkh(mid[2], mid[3]);
      shm4[s*4+2] = pkh(mid[4], mid[5]);
      shm4[s*4+3] = pkh(mid[6], mid[7]);
    }
  }
  __syncthreads();

  // ---- tail: pred_o = conv_tw(fc) + conv_W2P(mid) + bias ----
  int half = t >> 7, pi = t & 127;
  int tx = pi & 15, ty = pi >> 4;
  int slots[9];
  #pragma unroll
  for (int dy = 0; dy < 3; dy++)
    #pragma unroll
    for (int dx = 0; dx < 3; dx++)
      slots[dy*3 + dx] = sof[(ty + dy)*18 + (tx + dx)];
  const unsigned* TW2 = (const unsigned*)(ws + O_TW2);
  float a0, a1, a2;
  if (half == 0) { a0 = ws[O_TB+0]; a1 = ws[O_TB+1]; a2 = ws[O_TB+2]; }
  else           { a0 = 0.0f; a1 = 0.0f; a2 = 0.0f; }
  int cp0 = half*16;
  for (int cpl = 0; cpl < 16; cpl++) {
    int cp = cp0 + cpl;
    #pragma unroll
    for (int j = 0; j < 9; j++) {
      h2 hv = uh(shf[cp*181 + slots[j]]);
      a0 = FDOT2(hv, uh(TW2[(0*9 + j)*32 + cp]), a0);
      a1 = FDOT2(hv, uh(TW2[(1*9 + j)*32 + cp]), a1);
      a2 = FDOT2(hv, uh(TW2[(2*9 + j)*32 + cp]), a2);
    }
  }
  if (half == 0) {
    // mid contribution (cls-dependent combined weights)
    #pragma unroll
    for (int j = 0; j < 9; j++) {
      int sl = slots[j];
      int cl = scls[sl];
      uint4 mv = *(const uint4*)&shm4[sl*4];
      const uint4* Wp = (const uint4*)((const unsigned*)(ws + O_W2P)) + (cl*9 + j)*3;
      uint4 w0 = Wp[0], w1 = Wp[1], w2 = Wp[2];
      h2 m0 = uh(mv.x), m1 = uh(mv.y), m2 = uh(mv.z), m3 = uh(mv.w);
      a0 = FDOT2(m0, uh(w0.x), a0); a0 = FDOT2(m1, uh(w0.y), a0);
      a0 = FDOT2(m2, uh(w0.z), a0); a0 = FDOT2(m3, uh(w0.w), a0);
      a1 = FDOT2(m0, uh(w1.x), a1); a1 = FDOT2(m1, uh(w1.y), a1);
      a1 = FDOT2(m2, uh(w1.z), a1); a1 = FDOT2(m3, uh(w1.w), a1);
      a2 = FDOT2(m0, uh(w2.x), a2); a2 = FDOT2(m1, uh(w2.y), a2);
      a2 = FDOT2(m2, uh(w2.z), a2); a2 = FDOT2(m3, uh(w2.w), a2);
    }
  }
  if (half == 1) {
    spart[pi*3+0] = a0; spart[pi*3+1] = a1; spart[pi*3+2] = a2;
  }
  __syncthreads();
  if (half == 0) {
    a0 += spart[pi*3+0]; a1 += spart[pi*3+1]; a2 += spart[pi*3+2];
    int p = (ty0 + ty)*WSZ + (tx0 + tx);
    pred[p*3 + 0] = a0;
    pred[p*3 + 1] = a1;
    pred[p*3 + 2] = a2;
  }
}

// ==== K3: query gather ====
__global__ __launch_bounds__(256) void k_gather(const void* __restrict__ inp,
                                                const void* __restrict__ coord, const void* __restrict__ cell,
                                                const float* __restrict__ ws, void* __restrict__ outp) {
  bool f32m = sniff_f32(inp);
  const float* pred = ws + O_PRED;
  int q = blockIdx.x*256 + threadIdx.x;
  float cy = rdin(coord, q*2 + 0, f32m);
  float cx = rdin(coord, q*2 + 1, f32m);
  float ly = rdin(cell, q*2 + 0, f32m);
  float lx = rdin(cell, q*2 + 1, f32m);
  float gyq = fminf(fmaxf(cy - ly*0.5f + 1e-6f, -1.0f + 1e-6f), 1.0f - 1e-6f);
  float gxq = fminf(fmaxf(cx - lx*0.5f + 1e-6f, -1.0f + 1e-6f), 1.0f - 1e-6f);
  int xi = (int)rintf((gxq + 1.0f)*0.5f*511.0f);
  int yi = (int)rintf((gyq + 1.0f)*0.5f*511.0f);
  xi = min(max(xi, 0), WSZ-1);
  yi = min(max(yi, 0), HS-1);
  int pp = yi*WSZ + xi;
  float v0 = pred[pp*3 + 0], v1 = pred[pp*3 + 1], v2 = pred[pp*3 + 2];
  if (f32m) {
    float* o = (float*)outp;
    o[q*3 + 0] = v0; o[q*3 + 1] = v1; o[q*3 + 2] = v2;
  } else {
    bf16* o = (bf16*)outp;
    o[q*3 + 0] = __float2bfloat16(v0);
    o[q*3 + 1] = __float2bfloat16(v1);
    o[q*3 + 2] = __float2bfloat16(v2);
  }
}

extern "C" void kernel_launch(void* const* d_in, const int* in_sizes, int n_in,
                              void* d_out, int out_size, void* d_ws, size_t ws_size,
                              hipStream_t stream) {
  const void* inp   = d_in[0];
  const void* coord = d_in[1];
  const void* cell  = d_in[2];
  const void* encw  = d_in[3];
  const void* encb  = d_in[4];
  const void* w1    = d_in[5];
  const void* b1    = d_in[6];
  const void* w2    = d_in[7];
  const void* b2    = d_in[8];
  const void* rw    = d_in[9];
  const void* rb    = d_in[10];
  const void* ow    = d_in[11];
  const void* ob    = d_in[12];
  const void* tw    = d_in[13];
  const void* tb    = d_in[14];
  const void* wc    = d_in[15];
  const void* we    = d_in[16];

  float* wsf  = (float*)d_ws;
  float* pred = wsf + O_PRED;

  k_prep<<<273, 64, 0, stream>>>(inp, encw, encb, w1, b1, w2, b2, rw, rb, ow, ob, tw, tb, wc, we, wsf);
  k_maintail<<<2048, 256, 0, stream>>>(wsf, pred);
  k_gather<<<1024, 256, 0, stream>>>(inp, coord, cell, wsf, d_out);
}

// Round 8
// 210.591 us; speedup vs baseline: 1.8693x; 1.2621x over previous
//
#include <hip/hip_runtime.h>
#include <hip/hip_bf16.h>

typedef __hip_bfloat16 bf16;
typedef __fp16 h2 __attribute__((ext_vector_type(2)));   // matches V2h of amdgcn builtins

__device__ __forceinline__ float bf2f(bf16 h) { return __bfloat162float(h); }
__device__ __forceinline__ bf16 us2bf(unsigned short u){ union{unsigned short s; bf16 h;}v; v.s=u; return v.h; }
__device__ __forceinline__ float asf(unsigned u){ union{unsigned u; float f;}v; v.u=u; return v.f; }
__device__ __forceinline__ h2 uh(unsigned u){ union{unsigned u; h2 h;}v; v.u=u; return v.h; }
__device__ __forceinline__ unsigned pkh(float a, float b){ union{h2 h; unsigned u;}v; v.h=__builtin_amdgcn_cvt_pkrtz(a,b); return v.u; }
__device__ __forceinline__ unsigned short f2bu(float a){ union{bf16 h; unsigned short u;}v; v.h=__float2bfloat16(a); return v.u; }
__device__ __forceinline__ unsigned pkbf(float a, float b){ return ((unsigned)f2bu(b) << 16) | (unsigned)f2bu(a); }
#define FDOT2(va,vb,acc) __builtin_amdgcn_fdot2((va),(vb),(acc),false)

#define HH 128
#define WW 128
#define HS 512
#define WSZ 512
#define QN (HS*WSZ)

// ---- ws dword-offset layout (~6.3 MB) ----
#define O_OFFTAB 0        // 32 f32
#define O_TB     32       // 3 f32
#define O_TW2    64       // 864 u32: tail weights f16 pairs [o][j][cpair]
#define O_CWC2   1024     // 4096 u32: f16 pairs [cls][cpair][k]
#define O_W2P    5120     // 1728 u32: f16 pairs [cls][j][o][kpair]
#define O_FEAT   8192     // 1048576 f32 HWC
#define O_PRED   1056768  // 524288 u32: bf16x4-packed pred, block-sorted [blk][pi]

// class-sorted halo decode prefix for 10x18 halo (classes by ((p+3)&3))
__constant__ int PREF2[16] = {0,15,27,39,54,64,72,80,90,100,108,116,126,141,153,165};

__device__ __forceinline__ float rdin(const void* p, int i, bool f32m) {
  return f32m ? ((const float*)p)[i] : bf2f(((const bf16*)p)[i]);
}
// uniform-index-friendly read (dword load + shift)
__device__ __forceinline__ float rdw(const void* p, int i, bool f32m) {
  if (f32m) return ((const float*)p)[i];
  unsigned u = ((const unsigned*)p)[i>>1];
  return asf((i&1) ? (u & 0xffff0000u) : (u<<16));
}
// per-wave dtype sniff: true => f32 inputs
__device__ __forceinline__ bool sniff_f32(const void* inp) {
  int lane = threadIdx.x & 63;
  unsigned short u = ((const unsigned short*)inp)[2*lane];
  float v = bf2f(us2bf(u));
  bool ok = (v == v) && (fabsf(v) < 64.0f);
  return __popcll(__ballot(ok)) < 48;
}

// ==== K1: encoder conv + per-class MLP/combined-weights + weight packing ====
__global__ __launch_bounds__(256) void k_prep(
    const void* __restrict__ inp, const void* __restrict__ encw, const void* __restrict__ encb,
    const void* __restrict__ w1, const void* __restrict__ b1,
    const void* __restrict__ w2, const void* __restrict__ b2,
    const void* __restrict__ rw, const void* __restrict__ rb,
    const void* __restrict__ ow, const void* __restrict__ ob,
    const void* __restrict__ tw, const void* __restrict__ tb,
    const void* __restrict__ wc, const void* __restrict__ we,
    float* __restrict__ ws) {
  __shared__ float shw[448];
  __shared__ float shb[16];
  __shared__ float sh1[64];
  __shared__ float sh2[64];
  __shared__ float shr[4];
  __shared__ float shcwe[512];
  bool f32m = sniff_f32(inp);
  int b = blockIdx.x, t = threadIdx.x;

  if (b < 256) {
    // ---- encoder conv 3->64: block = (channel-group g, 256-px tile) ----
    int g = b >> 6;                 // 0..3 -> oc [g*16, g*16+16)
    int px = (b & 63)*256 + t;      // 0..16383
    for (int i = t; i < 432; i += 256) shw[i] = rdw(encw, g*432 + i, f32m);
    if (t < 16) shb[t] = rdw(encb, g*16 + t, f32m);
    __syncthreads();
    int x = px & 127, y = px >> 7;
    float tp[27];
    #pragma unroll
    for (int ic = 0; ic < 3; ic++)
      #pragma unroll
      for (int dy = 0; dy < 3; dy++) {
        int yy = y + dy - 1;
        #pragma unroll
        for (int dx = 0; dx < 3; dx++) {
          int xx = x + dx - 1;
          bool ok = (yy >= 0) & (yy < 128) & (xx >= 0) & (xx < 128);
          tp[ic*9 + dy*3 + dx] = ok ? rdin(inp, ic*16384 + yy*128 + xx, f32m) : 0.0f;
        }
      }
    float* out = ws + O_FEAT + (size_t)px*64 + g*16;
    #pragma unroll
    for (int o4 = 0; o4 < 4; o4++) {
      float a[4];
      #pragma unroll
      for (int oo = 0; oo < 4; oo++) {
        int o2 = o4*4 + oo;
        float acc = shb[o2];
        #pragma unroll
        for (int kk = 0; kk < 27; kk++) acc = fmaf(shw[o2*27 + kk], tp[kk], acc);
        a[oo] = acc;
      }
      *(float4*)(out + o4*4) = make_float4(a[0], a[1], a[2], a[3]);
    }
  } else if (b < 272) {
    // ---- per-class MLP -> off, r; fold into CWC2 / W2P ----
    int cls = b - 256;
    if (t < 64) {
      float mcls = (float)(cls >> 2), ncls = (float)(cls & 3);
      float chv = (mcls + 0.5f)*0.25f - 0.5f;
      float cwv = (ncls + 0.5f)*0.25f - 0.5f;
      float s1 = rdw(w1,t*4+0,f32m)*0.25f + rdw(w1,t*4+1,f32m)*0.25f
               + rdw(w1,t*4+2,f32m)*chv + rdw(w1,t*4+3,f32m)*cwv + rdw(b1,t,f32m);
      sh1[t] = fmaxf(s1, 0.0f);
    }
    __syncthreads();
    if (t < 64) {
      float s2 = rdw(b2,t,f32m);
      for (int i = 0; i < 64; i++) s2 = fmaf(rdw(w2,t*64+i,f32m), sh1[i], s2);
      sh2[t] = fmaxf(s2, 0.0f);
    }
    __syncthreads();
    if (t < 2) {
      float a = rdw(ob,t,f32m);
      for (int i = 0; i < 64; i++) a = fmaf(rdw(ow,t*64+i,f32m), sh2[i], a);
      ws[O_OFFTAB + cls*2 + t] = a;
    } else if (t < 6) {
      int e = t - 2;
      float a = rdw(rb,e,f32m);
      for (int i = 0; i < 64; i++) a = fmaf(rdw(rw,e*64+i,f32m), sh2[i], a);
      shr[e] = 1.0f / (1.0f + expf(-a));
    }
    __syncthreads();
    float r0 = shr[0], r1 = shr[1], r2 = shr[2], r3 = shr[3];
    // CWE (f32, LDS only): cwe[c*8+k] = sum_e r_e we[e][c][k]
    for (int idx = t; idx < 512; idx += 256) {
      float a =       r0 * rdw(we,        idx, f32m);
      a = fmaf(r1, rdw(we,  512 + idx, f32m), a);
      a = fmaf(r2, rdw(we, 1024 + idx, f32m), a);
      a = fmaf(r3, rdw(we, 1536 + idx, f32m), a);
      shcwe[idx] = a;
    }
    // CWC2 [cls][cp][k] f16 pairs over channel pair
    unsigned* wcw = (unsigned*)(ws + O_CWC2) + cls*256;
    for (int idx = t; idx < 256; idx += 256) {
      int cp = idx >> 3, k = idx & 7;
      float lo =       r0 * rdw(wc,        k*64 + 2*cp, f32m);
      lo = fmaf(r1, rdw(wc,  512 + k*64 + 2*cp, f32m), lo);
      lo = fmaf(r2, rdw(wc, 1024 + k*64 + 2*cp, f32m), lo);
      lo = fmaf(r3, rdw(wc, 1536 + k*64 + 2*cp, f32m), lo);
      float hi =       r0 * rdw(wc,        k*64 + 2*cp + 1, f32m);
      hi = fmaf(r1, rdw(wc,  512 + k*64 + 2*cp + 1, f32m), hi);
      hi = fmaf(r2, rdw(wc, 1024 + k*64 + 2*cp + 1, f32m), hi);
      hi = fmaf(r3, rdw(wc, 1536 + k*64 + 2*cp + 1, f32m), hi);
      wcw[idx] = pkh(lo, hi);
    }
    __syncthreads();   // shcwe ready
    // W2P [cls][j][o][kpair]: W2[o][k][j] = sum_c tw[o][c][j] * cwe[c][k]
    unsigned* wpp = (unsigned*)(ws + O_W2P);
    for (int idx = t; idx < 108; idx += 256) {
      int j = idx / 12, rem = idx - j*12, o2 = rem >> 2, kp = rem & 3;
      float alo = 0.0f, ahi = 0.0f;
      for (int c = 0; c < 64; c++) {
        float tv = rdw(tw, (o2*64 + c)*9 + j, f32m);
        alo = fmaf(tv, shcwe[c*8 + 2*kp],     alo);
        ahi = fmaf(tv, shcwe[c*8 + 2*kp + 1], ahi);
      }
      wpp[(cls*9 + j)*12 + o2*4 + kp] = pkh(alo, ahi);
    }
  } else {
    // ---- misc: pack tail weights TW2 [o][j][cpair], TB ----
    for (int idx = t; idx < 864; idx += 256) {
      int o2 = idx / 288, rem = idx - o2*288, j = rem >> 5, cp = rem & 31;
      unsigned d = pkh(rdw(tw, (o2*64 + 2*cp    )*9 + j, f32m),
                       rdw(tw, (o2*64 + 2*cp + 1)*9 + j, f32m));
      ((unsigned*)(ws + O_TW2))[idx] = d;
    }
    if (t < 3) ws[O_TB + t] = rdin(tb, t, f32m);
  }
}

// ==== K2: fused main+tail, tile 8x16, halo 10x18, f16/dot2 ====
__global__ __launch_bounds__(256) void k_maintail(const float* __restrict__ ws, unsigned* __restrict__ pred4) {
  __shared__ unsigned shf[32*181];               // fc f16 pairs [cpair][slot], 23168 B
  __shared__ __align__(16) unsigned shm4[181*4]; // mid f16 pairs [slot][kpair]
  __shared__ unsigned short sof[192];            // pos -> slot
  __shared__ unsigned short scls[192];           // slot -> cls
  __shared__ float spart[128*3];
  int blk = blockIdx.x;                          // 0..2047
  int xcd = blk & 7, local = blk >> 3;           // XCD-banded for L2 locality
  int ty0 = (xcd*8 + (local >> 5)) * 8;
  int tx0 = (local & 31) * 16;
  int t = threadIdx.x;
  const float4* Fv = (const float4*)(ws + O_FEAT);

  if (t < 180) {
    int s = t;
    int cls = 0;
    #pragma unroll
    for (int i = 1; i < 16; i++) cls += (s >= PREF2[i]) ? 1 : 0;
    int j = s - PREF2[cls];
    int a = cls >> 2, bb = cls & 3;
    int nx = ((bb == 0) | (bb == 3)) ? 5 : 4;
    int jy = (nx == 4) ? (j >> 2) : ((j*13) >> 6);
    int jx = j - jy*nx;
    int py = ((a + 1) & 3) + 4*jy;
    int px = ((bb + 1) & 3) + 4*jx;
    int pos = py*18 + px;
    sof[pos] = (unsigned short)s;
    int gy = ty0 - 1 + py, gx = tx0 - 1 + px;
    if ((gy < 0) | (gy >= HS) | (gx < 0) | (gx >= WSZ)) {
      scls[s] = 0;
      #pragma unroll
      for (int cp = 0; cp < 32; cp++) shf[cp*181 + s] = 0u;
      shm4[s*4+0] = 0u; shm4[s*4+1] = 0u; shm4[s*4+2] = 0u; shm4[s*4+3] = 0u;
    } else {
      scls[s] = (unsigned short)cls;
      float off0 = ws[O_OFFTAB + cls*2 + 0];
      float off1 = ws[O_OFFTAB + cls*2 + 1];
      float gxf = (((float)gx + 0.5f)*0.25f - 0.5f)*(2.0f/127.0f) - 1.0f + off0*(2.0f/127.0f);
      float gyf = (((float)gy + 0.5f)*0.25f - 0.5f)*(2.0f/127.0f) - 1.0f + off1*(2.0f/127.0f);
      float sx = (gxf + 1.0f)*0.5f*127.0f;
      float sy = (gyf + 1.0f)*0.5f*127.0f;
      float x0f = floorf(sx), y0f = floorf(sy);
      float fx = sx - x0f, fy = sy - y0f;
      int ix0 = (int)x0f, iy0 = (int)y0f;
      int ix1 = ix0 + 1, iy1 = iy0 + 1;
      float wx0 = 1.0f - fx, wy0 = 1.0f - fy;
      float w00 = wy0*wx0, w01 = wy0*fx, w10 = fy*wx0, w11 = fy*fx;
      bool vx0 = (ix0 >= 0) & (ix0 < WW), vx1 = (ix1 >= 0) & (ix1 < WW);
      bool vy0 = (iy0 >= 0) & (iy0 < HH), vy1 = (iy1 >= 0) & (iy1 < HH);
      if (!(vy0 & vx0)) w00 = 0.0f;
      if (!(vy0 & vx1)) w01 = 0.0f;
      if (!(vy1 & vx0)) w10 = 0.0f;
      if (!(vy1 & vx1)) w11 = 0.0f;
      int cx0 = min(max(ix0, 0), WW-1), cx1 = min(max(ix1, 0), WW-1);
      int cy0 = min(max(iy0, 0), HH-1), cy1 = min(max(iy1, 0), HH-1);
      int b00 = (cy0*WW + cx0)*16, b01 = (cy0*WW + cx1)*16;
      int b10 = (cy1*WW + cx0)*16, b11 = (cy1*WW + cx1)*16;

      const unsigned* CW2 = (const unsigned*)(ws + O_CWC2) + cls*256;
      float mid[8] = {0,0,0,0,0,0,0,0};
      #pragma unroll 2
      for (int cg = 0; cg < 16; cg++) {
        float4 t00 = Fv[b00 + cg], t01 = Fv[b01 + cg];
        float4 t10 = Fv[b10 + cg], t11 = Fv[b11 + cg];
        float4 f;
        f.x = fmaf(w00,t00.x, fmaf(w01,t01.x, fmaf(w10,t10.x, w11*t11.x)));
        f.y = fmaf(w00,t00.y, fmaf(w01,t01.y, fmaf(w10,t10.y, w11*t11.y)));
        f.z = fmaf(w00,t00.z, fmaf(w01,t01.z, fmaf(w10,t10.z, w11*t11.z)));
        f.w = fmaf(w00,t00.w, fmaf(w01,t01.w, fmaf(w10,t10.w, w11*t11.w)));
        unsigned p0 = pkh(f.x, f.y), p1 = pkh(f.z, f.w);
        shf[(2*cg    )*181 + s] = p0;
        shf[(2*cg + 1)*181 + s] = p1;
        const uint4* Ck = (const uint4*)(CW2 + cg*16);
        uint4 c0 = Ck[0], c1 = Ck[1], d0 = Ck[2], d1 = Ck[3];
        h2 h0 = uh(p0), h1 = uh(p1);
        mid[0] = FDOT2(h0, uh(c0.x), mid[0]); mid[0] = FDOT2(h1, uh(d0.x), mid[0]);
        mid[1] = FDOT2(h0, uh(c0.y), mid[1]); mid[1] = FDOT2(h1, uh(d0.y), mid[1]);
        mid[2] = FDOT2(h0, uh(c0.z), mid[2]); mid[2] = FDOT2(h1, uh(d0.z), mid[2]);
        mid[3] = FDOT2(h0, uh(c0.w), mid[3]); mid[3] = FDOT2(h1, uh(d0.w), mid[3]);
        mid[4] = FDOT2(h0, uh(c1.x), mid[4]); mid[4] = FDOT2(h1, uh(d1.x), mid[4]);
        mid[5] = FDOT2(h0, uh(c1.y), mid[5]); mid[5] = FDOT2(h1, uh(d1.y), mid[5]);
        mid[6] = FDOT2(h0, uh(c1.z), mid[6]); mid[6] = FDOT2(h1, uh(d1.z), mid[6]);
        mid[7] = FDOT2(h0, uh(c1.w), mid[7]); mid[7] = FDOT2(h1, uh(d1.w), mid[7]);
      }
      shm4[s*4+0] = pkh(mid[0], mid[1]);
      shm4[s*4+1] = pkh(mid[2], mid[3]);
      shm4[s*4+2] = pkh(mid[4], mid[5]);
      shm4[s*4+3] = pkh(mid[6], mid[7]);
    }
  }
  __syncthreads();

  // ---- tail: pred_o = conv_tw(fc) + conv_W2P(mid) + bias ----
  // pixels iterated class-sorted: pi = cls*8 + tyi*4 + txi
  int half = t >> 7, pi = t & 127;
  int cpx = pi >> 3, idx = pi & 7;
  int ty = (cpx >> 2) + 4*(idx >> 2);
  int tx = (cpx & 3) + 4*(idx & 3);
  int slots[9];
  #pragma unroll
  for (int dy = 0; dy < 3; dy++)
    #pragma unroll
    for (int dx = 0; dx < 3; dx++)
      slots[dy*3 + dx] = sof[(ty + dy)*18 + (tx + dx)];
  const unsigned* TW2 = (const unsigned*)(ws + O_TW2);
  float a0, a1, a2;
  if (half == 0) { a0 = ws[O_TB+0]; a1 = ws[O_TB+1]; a2 = ws[O_TB+2]; }
  else           { a0 = 0.0f; a1 = 0.0f; a2 = 0.0f; }
  int cp0 = half*16;
  for (int cpl = 0; cpl < 16; cpl++) {
    int cp = cp0 + cpl;
    #pragma unroll
    for (int j = 0; j < 9; j++) {
      h2 hv = uh(shf[cp*181 + slots[j]]);
      a0 = FDOT2(hv, uh(TW2[(0*9 + j)*32 + cp]), a0);
      a1 = FDOT2(hv, uh(TW2[(1*9 + j)*32 + cp]), a1);
      a2 = FDOT2(hv, uh(TW2[(2*9 + j)*32 + cp]), a2);
    }
  }
  // mid contribution split by j across halves: half0 j 0..4, half1 j 5..8
  {
    int jb = (half == 0) ? 0 : 5;
    int je = (half == 0) ? 5 : 9;
    for (int j = jb; j < je; j++) {
      int sl = slots[j];
      int cl = scls[sl];
      uint4 mv = *(const uint4*)&shm4[sl*4];
      const uint4* Wp = (const uint4*)((const unsigned*)(ws + O_W2P)) + (cl*9 + j)*3;
      uint4 w0 = Wp[0], w1 = Wp[1], w2 = Wp[2];
      h2 m0 = uh(mv.x), m1 = uh(mv.y), m2 = uh(mv.z), m3 = uh(mv.w);
      a0 = FDOT2(m0, uh(w0.x), a0); a0 = FDOT2(m1, uh(w0.y), a0);
      a0 = FDOT2(m2, uh(w0.z), a0); a0 = FDOT2(m3, uh(w0.w), a0);
      a1 = FDOT2(m0, uh(w1.x), a1); a1 = FDOT2(m1, uh(w1.y), a1);
      a1 = FDOT2(m2, uh(w1.z), a1); a1 = FDOT2(m3, uh(w1.w), a1);
      a2 = FDOT2(m0, uh(w2.x), a2); a2 = FDOT2(m1, uh(w2.y), a2);
      a2 = FDOT2(m2, uh(w2.z), a2); a2 = FDOT2(m3, uh(w2.w), a2);
    }
  }
  if (half == 1) {
    spart[pi*3+0] = a0; spart[pi*3+1] = a1; spart[pi*3+2] = a2;
  }
  __syncthreads();
  if (half == 0) {
    a0 += spart[pi*3+0]; a1 += spart[pi*3+1]; a2 += spart[pi*3+2];
    // packed bf16x4 store, block-sorted layout [blk][pi] -> coalesced dwordx2
    ((uint2*)pred4)[blk*128 + pi] = make_uint2(pkbf(a0, a1), pkbf(a2, 0.0f));
  }
}

// ==== K3: query gather ====
__global__ __launch_bounds__(256) void k_gather(const void* __restrict__ inp,
                                                const void* __restrict__ coord, const void* __restrict__ cell,
                                                const float* __restrict__ ws, void* __restrict__ outp) {
  bool f32m = sniff_f32(inp);
  const uint2* pred4 = (const uint2*)((const unsigned*)(ws + O_PRED));
  int q = blockIdx.x*256 + threadIdx.x;
  float cy, cx, ly, lx;
  if (f32m) {
    float2 c = ((const float2*)coord)[q]; cy = c.x; cx = c.y;
    float2 l = ((const float2*)cell)[q];  ly = l.x; lx = l.y;
  } else {
    unsigned cu = ((const unsigned*)coord)[q]; cy = asf(cu<<16); cx = asf(cu & 0xffff0000u);
    unsigned lu = ((const unsigned*)cell)[q];  ly = asf(lu<<16); lx = asf(lu & 0xffff0000u);
  }
  float gyq = fminf(fmaxf(cy - ly*0.5f + 1e-6f, -1.0f + 1e-6f), 1.0f - 1e-6f);
  float gxq = fminf(fmaxf(cx - lx*0.5f + 1e-6f, -1.0f + 1e-6f), 1.0f - 1e-6f);
  int xi = (int)rintf((gxq + 1.0f)*0.5f*511.0f);
  int yi = (int)rintf((gyq + 1.0f)*0.5f*511.0f);
  xi = min(max(xi, 0), WSZ-1);
  yi = min(max(yi, 0), HS-1);
  // invert block-sorted layout
  int row = yi >> 3, col = xi >> 4;
  int xcd = row >> 3;
  int local = (row & 7)*32 + col;
  int blk = local*8 + xcd;
  int cls = (yi & 3)*4 + (xi & 3);
  int pi = cls*8 + ((yi >> 2) & 1)*4 + ((xi >> 2) & 3);
  uint2 d = pred4[blk*128 + pi];
  float v0 = asf(d.x << 16), v1 = asf(d.x & 0xffff0000u), v2 = asf(d.y << 16);
  if (f32m) {
    float* o = (float*)outp;
    o[q*3 + 0] = v0; o[q*3 + 1] = v1; o[q*3 + 2] = v2;
  } else {
    bf16* o = (bf16*)outp;
    o[q*3 + 0] = __float2bfloat16(v0);
    o[q*3 + 1] = __float2bfloat16(v1);
    o[q*3 + 2] = __float2bfloat16(v2);
  }
}

extern "C" void kernel_launch(void* const* d_in, const int* in_sizes, int n_in,
                              void* d_out, int out_size, void* d_ws, size_t ws_size,
                              hipStream_t stream) {
  const void* inp   = d_in[0];
  const void* coord = d_in[1];
  const void* cell  = d_in[2];
  const void* encw  = d_in[3];
  const void* encb  = d_in[4];
  const void* w1    = d_in[5];
  const void* b1    = d_in[6];
  const void* w2    = d_in[7];
  const void* b2    = d_in[8];
  const void* rw    = d_in[9];
  const void* rb    = d_in[10];
  const void* ow    = d_in[11];
  const void* ob    = d_in[12];
  const void* tw    = d_in[13];
  const void* tb    = d_in[14];
  const void* wc    = d_in[15];
  const void* we    = d_in[16];

  float* wsf = (float*)d_ws;
  unsigned* pred4 = (unsigned*)(wsf + O_PRED);

  k_prep<<<273, 256, 0, stream>>>(inp, encw, encb, w1, b1, w2, b2, rw, rb, ow, ob, tw, tb, wc, we, wsf);
  k_maintail<<<2048, 256, 0, stream>>>(wsf, pred4);
  k_gather<<<1024, 256, 0, stream>>>(inp, coord, cell, wsf, d_out);
}

// Round 9
// 176.842 us; speedup vs baseline: 2.2260x; 1.1908x over previous
//
#include <hip/hip_runtime.h>
#include <hip/hip_bf16.h>

typedef __hip_bfloat16 bf16;
typedef __fp16 h2 __attribute__((ext_vector_type(2)));   // matches V2h of amdgcn builtins

__device__ __forceinline__ float bf2f(bf16 h) { return __bfloat162float(h); }
__device__ __forceinline__ bf16 us2bf(unsigned short u){ union{unsigned short s; bf16 h;}v; v.s=u; return v.h; }
__device__ __forceinline__ float asf(unsigned u){ union{unsigned u; float f;}v; v.u=u; return v.f; }
__device__ __forceinline__ h2 uh(unsigned u){ union{unsigned u; h2 h;}v; v.u=u; return v.h; }
__device__ __forceinline__ unsigned pkh(float a, float b){ union{h2 h; unsigned u;}v; v.h=__builtin_amdgcn_cvt_pkrtz(a,b); return v.u; }
__device__ __forceinline__ unsigned short f2bu(float a){ union{bf16 h; unsigned short u;}v; v.h=__float2bfloat16(a); return v.u; }
__device__ __forceinline__ unsigned pkbf(float a, float b){ return ((unsigned)f2bu(b) << 16) | (unsigned)f2bu(a); }
#define FDOT2(va,vb,acc) __builtin_amdgcn_fdot2((va),(vb),(acc),false)

#define HH 128
#define WW 128
#define HS 512
#define WSZ 512
#define QN (HS*WSZ)

// ---- ws dword-offset layout ----
#define O_OFFTAB 0        // 32 f32
#define O_TB     32       // 3 f32
#define O_TW2    64       // 864 u32: tail weights f16 pairs [o][j][cpair]
#define O_CWC2   1024     // 4096 u32: f16 pairs [cls][cp][k]
#define O_W2P    5120     // 1728 u32: f16 pairs [cls][j][o][kpair]
#define O_FEAT   8192     // 524288 u32: feat packed f16 pairs, HWC [px][cp]
#define O_PRED   1056768  // 524288 u32: bf16x4-packed pred, block-sorted [blk][pi]

// k_prep LDS pool carve (f32 units)
#define SH_W2T 0          // 64*65 transposed w2
#define SH_WE  4160       // 2048
#define SH_WC  6208       // 2048
#define SH_TW  8256       // 1728
#define SH_OW  9984       // 128
#define SH_RW  10112      // 256
#define SH_END 10368

// class-sorted halo decode prefix for 10x18 halo (classes by ((p+3)&3))
__constant__ int PREF2[16] = {0,15,27,39,54,64,72,80,90,100,108,116,126,141,153,165};

__device__ __forceinline__ float rdin(const void* p, int i, bool f32m) {
  return f32m ? ((const float*)p)[i] : bf2f(((const bf16*)p)[i]);
}
__device__ __forceinline__ float rdw(const void* p, int i, bool f32m) {
  if (f32m) return ((const float*)p)[i];
  unsigned u = ((const unsigned*)p)[i>>1];
  return asf((i&1) ? (u & 0xffff0000u) : (u<<16));
}
__device__ __forceinline__ bool sniff_f32(const void* inp) {
  int lane = threadIdx.x & 63;
  unsigned short u = ((const unsigned short*)inp)[2*lane];
  float v = bf2f(us2bf(u));
  bool ok = (v == v) && (fabsf(v) < 64.0f);
  return __popcll(__ballot(ok)) < 48;
}
__device__ __forceinline__ unsigned blend4(unsigned a, unsigned b, unsigned c, unsigned d,
                                           h2 W00, h2 W01, h2 W10, h2 W11) {
  h2 f = uh(a)*W00 + uh(b)*W01 + uh(c)*W10 + uh(d)*W11;   // v_pk_fma_f16
  union{h2 h; unsigned u;} v; v.h = f; return v.u;
}

// ==== K1: encoder conv (f16-packed feat) + per-class MLP/weights (LDS-staged) ====
__global__ __launch_bounds__(256) void k_prep(
    const void* __restrict__ inp, const void* __restrict__ encw, const void* __restrict__ encb,
    const void* __restrict__ w1, const void* __restrict__ b1,
    const void* __restrict__ w2, const void* __restrict__ b2,
    const void* __restrict__ rw, const void* __restrict__ rb,
    const void* __restrict__ ow, const void* __restrict__ ob,
    const void* __restrict__ tw, const void* __restrict__ tb,
    const void* __restrict__ wc, const void* __restrict__ we,
    float* __restrict__ ws) {
  __shared__ float shpool[SH_END];
  __shared__ float sh1[64];
  __shared__ float sh2[64];
  __shared__ float shr[4];
  __shared__ float shcwe[512];
  bool f32m = sniff_f32(inp);
  int b = blockIdx.x, t = threadIdx.x;
  unsigned* wsu = (unsigned*)ws;

  if (b < 256) {
    // ---- encoder conv 3->64: block = (channel-group g, 256-px tile) ----
    int g = b >> 6;                 // oc [g*16, g*16+16)
    int px = (b & 63)*256 + t;
    float* shw = shpool;            // 432
    float* shb = shpool + 432;      // 16
    for (int i = t; i < 432; i += 256) shw[i] = rdw(encw, g*432 + i, f32m);
    if (t < 16) shb[t] = rdw(encb, g*16 + t, f32m);
    __syncthreads();
    int x = px & 127, y = px >> 7;
    float tp[27];
    #pragma unroll
    for (int ic = 0; ic < 3; ic++)
      #pragma unroll
      for (int dy = 0; dy < 3; dy++) {
        int yy = y + dy - 1;
        #pragma unroll
        for (int dx = 0; dx < 3; dx++) {
          int xx = x + dx - 1;
          bool ok = (yy >= 0) & (yy < 128) & (xx >= 0) & (xx < 128);
          tp[ic*9 + dy*3 + dx] = ok ? rdin(inp, ic*16384 + yy*128 + xx, f32m) : 0.0f;
        }
      }
    unsigned e[8];
    #pragma unroll
    for (int o4 = 0; o4 < 4; o4++) {
      float a[4];
      #pragma unroll
      for (int oo = 0; oo < 4; oo++) {
        int o2 = o4*4 + oo;
        float acc = shb[o2];
        #pragma unroll
        for (int kk = 0; kk < 27; kk++) acc = fmaf(shw[o2*27 + kk], tp[kk], acc);
        a[oo] = acc;
      }
      e[o4*2]   = pkh(a[0], a[1]);
      e[o4*2+1] = pkh(a[2], a[3]);
    }
    uint4* outp = (uint4*)(wsu + O_FEAT + px*32 + g*8);
    outp[0] = make_uint4(e[0], e[1], e[2], e[3]);
    outp[1] = make_uint4(e[4], e[5], e[6], e[7]);
  } else if (b < 272) {
    // ---- per-class MLP -> off, r; fold into CWC2 / W2P (all small weights LDS-staged) ----
    int cls = b - 256;
    for (int i = t; i < 4096; i += 256) shpool[SH_W2T + (i & 63)*65 + (i >> 6)] = rdw(w2, i, f32m);
    for (int i = t; i < 2048; i += 256) { shpool[SH_WE + i] = rdw(we, i, f32m); shpool[SH_WC + i] = rdw(wc, i, f32m); }
    for (int i = t; i < 1728; i += 256) shpool[SH_TW + i] = rdw(tw, i, f32m);
    for (int i = t; i < 128; i += 256)  shpool[SH_OW + i] = rdw(ow, i, f32m);
    for (int i = t; i < 256; i += 256)  shpool[SH_RW + i] = rdw(rw, i, f32m);
    if (t < 64) {
      float mcls = (float)(cls >> 2), ncls = (float)(cls & 3);
      float chv = (mcls + 0.5f)*0.25f - 0.5f;
      float cwv = (ncls + 0.5f)*0.25f - 0.5f;
      float s1 = rdw(w1,t*4+0,f32m)*0.25f + rdw(w1,t*4+1,f32m)*0.25f
               + rdw(w1,t*4+2,f32m)*chv + rdw(w1,t*4+3,f32m)*cwv + rdw(b1,t,f32m);
      sh1[t] = fmaxf(s1, 0.0f);
    }
    __syncthreads();
    if (t < 64) {
      float s2 = rdw(b2,t,f32m);
      for (int i = 0; i < 64; i++) s2 = fmaf(shpool[SH_W2T + i*65 + t], sh1[i], s2);
      sh2[t] = fmaxf(s2, 0.0f);
    }
    __syncthreads();
    if (t < 2) {
      float a = rdw(ob,t,f32m);
      for (int i = 0; i < 64; i++) a = fmaf(shpool[SH_OW + t*64 + i], sh2[i], a);
      ws[O_OFFTAB + cls*2 + t] = a;
    } else if (t < 6) {
      int e = t - 2;
      float a = rdw(rb,e,f32m);
      for (int i = 0; i < 64; i++) a = fmaf(shpool[SH_RW + e*64 + i], sh2[i], a);
      shr[e] = 1.0f / (1.0f + expf(-a));
    }
    __syncthreads();
    float r0 = shr[0], r1 = shr[1], r2 = shr[2], r3 = shr[3];
    // CWE (f32, LDS only): cwe[c*8+k]
    for (int idx = t; idx < 512; idx += 256) {
      float a =       r0 * shpool[SH_WE + idx];
      a = fmaf(r1, shpool[SH_WE +  512 + idx], a);
      a = fmaf(r2, shpool[SH_WE + 1024 + idx], a);
      a = fmaf(r3, shpool[SH_WE + 1536 + idx], a);
      shcwe[idx] = a;
    }
    // CWC2 [cls][cp][k] f16 pairs over channel pair
    unsigned* wcw = wsu + O_CWC2 + cls*256;
    for (int idx = t; idx < 256; idx += 256) {
      int cp = idx >> 3, k = idx & 7;
      float lo =       r0 * shpool[SH_WC +        k*64 + 2*cp];
      lo = fmaf(r1, shpool[SH_WC +  512 + k*64 + 2*cp], lo);
      lo = fmaf(r2, shpool[SH_WC + 1024 + k*64 + 2*cp], lo);
      lo = fmaf(r3, shpool[SH_WC + 1536 + k*64 + 2*cp], lo);
      float hi =       r0 * shpool[SH_WC +        k*64 + 2*cp + 1];
      hi = fmaf(r1, shpool[SH_WC +  512 + k*64 + 2*cp + 1], hi);
      hi = fmaf(r2, shpool[SH_WC + 1024 + k*64 + 2*cp + 1], hi);
      hi = fmaf(r3, shpool[SH_WC + 1536 + k*64 + 2*cp + 1], hi);
      wcw[idx] = pkh(lo, hi);
    }
    __syncthreads();   // shcwe ready
    // W2P [cls][j][o][kpair]: W2[o][k][j] = sum_c tw[o][c][j] * cwe[c][k]
    unsigned* wpp = wsu + O_W2P;
    for (int idx = t; idx < 108; idx += 256) {
      int j = idx / 12, rem = idx - j*12, o2 = rem >> 2, kp = rem & 3;
      float alo = 0.0f, ahi = 0.0f;
      for (int c = 0; c < 64; c++) {
        float tv = shpool[SH_TW + (o2*64 + c)*9 + j];
        alo = fmaf(tv, shcwe[c*8 + 2*kp],     alo);
        ahi = fmaf(tv, shcwe[c*8 + 2*kp + 1], ahi);
      }
      wpp[(cls*9 + j)*12 + o2*4 + kp] = pkh(alo, ahi);
    }
  } else {
    // ---- misc: pack tail weights TW2 [o][j][cpair], TB ----
    for (int idx = t; idx < 864; idx += 256) {
      int o2 = idx / 288, rem = idx - o2*288, j = rem >> 5, cp = rem & 31;
      unsigned d = pkh(rdw(tw, (o2*64 + 2*cp    )*9 + j, f32m),
                       rdw(tw, (o2*64 + 2*cp + 1)*9 + j, f32m));
      (wsu + O_TW2)[idx] = d;
    }
    if (t < 3) ws[O_TB + t] = rdin(tb, t, f32m);
  }
}

// ==== K2: fused main+tail, tile 8x16, halo 10x18, f16 feat, 2-lane phase A ====
__global__ __launch_bounds__(256) void k_maintail(const float* __restrict__ ws, unsigned* __restrict__ pred4) {
  __shared__ unsigned shf[32*181];               // fc f16 pairs [cp][slot], 23168 B
  __shared__ __align__(16) unsigned shm4[181*4]; // mid f16 pairs [slot][kpair]
  __shared__ unsigned short sof[192];            // pos -> slot
  __shared__ unsigned short scls[192];           // slot -> cls
  __shared__ float spart[128*3];
  const unsigned* wsu = (const unsigned*)ws;
  int blk = blockIdx.x;                          // 0..2047
  int xcd = blk & 7, local = blk >> 3;           // XCD-banded for L2 locality
  int ty0 = (xcd*8 + (local >> 5)) * 8;
  int tx0 = (local & 31) * 16;
  int t = threadIdx.x;
  int q = t & 1;                                 // channel-half (32 ch each)
  const uint4* F2 = (const uint4*)(wsu + O_FEAT);

  for (int s0 = 0; s0 < 256; s0 += 128) {
    int s = s0 + (t >> 1);
    if (s >= 180) continue;
    int cls = 0;
    #pragma unroll
    for (int i = 1; i < 16; i++) cls += (s >= PREF2[i]) ? 1 : 0;
    int j = s - PREF2[cls];
    int a = cls >> 2, bb = cls & 3;
    int nx = ((bb == 0) | (bb == 3)) ? 5 : 4;
    int jy = (nx == 4) ? (j >> 2) : ((j*13) >> 6);
    int jx = j - jy*nx;
    int py = ((a + 1) & 3) + 4*jy;
    int px = ((bb + 1) & 3) + 4*jx;
    int pos = py*18 + px;
    if (q == 0) sof[pos] = (unsigned short)s;
    int gy = ty0 - 1 + py, gx = tx0 - 1 + px;
    if ((gy < 0) | (gy >= HS) | (gx < 0) | (gx >= WSZ)) {
      if (q == 0) scls[s] = 0;
      #pragma unroll
      for (int i = 0; i < 16; i++) shf[(q*16 + i)*181 + s] = 0u;
      shm4[s*4 + q*2 + 0] = 0u;
      shm4[s*4 + q*2 + 1] = 0u;
      continue;
    }
    if (q == 0) scls[s] = (unsigned short)cls;
    float off0 = ws[O_OFFTAB + cls*2 + 0];
    float off1 = ws[O_OFFTAB + cls*2 + 1];
    float gxf = (((float)gx + 0.5f)*0.25f - 0.5f)*(2.0f/127.0f) - 1.0f + off0*(2.0f/127.0f);
    float gyf = (((float)gy + 0.5f)*0.25f - 0.5f)*(2.0f/127.0f) - 1.0f + off1*(2.0f/127.0f);
    float sx = (gxf + 1.0f)*0.5f*127.0f;
    float sy = (gyf + 1.0f)*0.5f*127.0f;
    float x0f = floorf(sx), y0f = floorf(sy);
    float fx = sx - x0f, fy = sy - y0f;
    int ix0 = (int)x0f, iy0 = (int)y0f;
    int ix1 = ix0 + 1, iy1 = iy0 + 1;
    float wx0 = 1.0f - fx, wy0 = 1.0f - fy;
    float w00 = wy0*wx0, w01 = wy0*fx, w10 = fy*wx0, w11 = fy*fx;
    bool vx0 = (ix0 >= 0) & (ix0 < WW), vx1 = (ix1 >= 0) & (ix1 < WW);
    bool vy0 = (iy0 >= 0) & (iy0 < HH), vy1 = (iy1 >= 0) & (iy1 < HH);
    if (!(vy0 & vx0)) w00 = 0.0f;
    if (!(vy0 & vx1)) w01 = 0.0f;
    if (!(vy1 & vx0)) w10 = 0.0f;
    if (!(vy1 & vx1)) w11 = 0.0f;
    int cx0 = min(max(ix0, 0), WW-1), cx1 = min(max(ix1, 0), WW-1);
    int cy0 = min(max(iy0, 0), HH-1), cy1 = min(max(iy1, 0), HH-1);
    // uint4 bases into packed-f16 feat (8 uint4 per px, lane-half q takes 4)
    int b00 = (cy0*WW + cx0)*8 + q*4, b01 = (cy0*WW + cx1)*8 + q*4;
    int b10 = (cy1*WW + cx0)*8 + q*4, b11 = (cy1*WW + cx1)*8 + q*4;

    // batch ALL 16 tap loads -> forced wide load window
    uint4 A0 = F2[b00+0], A1 = F2[b00+1], A2 = F2[b00+2], A3 = F2[b00+3];
    uint4 B0 = F2[b01+0], B1 = F2[b01+1], B2 = F2[b01+2], B3 = F2[b01+3];
    uint4 C0 = F2[b10+0], C1 = F2[b10+1], C2 = F2[b10+2], C3 = F2[b10+3];
    uint4 D0 = F2[b11+0], D1 = F2[b11+1], D2 = F2[b11+2], D3 = F2[b11+3];

    h2 W00 = { (__fp16)w00, (__fp16)w00 };
    h2 W01 = { (__fp16)w01, (__fp16)w01 };
    h2 W10 = { (__fp16)w10, (__fp16)w10 };
    h2 W11 = { (__fp16)w11, (__fp16)w11 };

    unsigned fp[16];
    fp[ 0] = blend4(A0.x,B0.x,C0.x,D0.x,W00,W01,W10,W11);
    fp[ 1] = blend4(A0.y,B0.y,C0.y,D0.y,W00,W01,W10,W11);
    fp[ 2] = blend4(A0.z,B0.z,C0.z,D0.z,W00,W01,W10,W11);
    fp[ 3] = blend4(A0.w,B0.w,C0.w,D0.w,W00,W01,W10,W11);
    fp[ 4] = blend4(A1.x,B1.x,C1.x,D1.x,W00,W01,W10,W11);
    fp[ 5] = blend4(A1.y,B1.y,C1.y,D1.y,W00,W01,W10,W11);
    fp[ 6] = blend4(A1.z,B1.z,C1.z,D1.z,W00,W01,W10,W11);
    fp[ 7] = blend4(A1.w,B1.w,C1.w,D1.w,W00,W01,W10,W11);
    fp[ 8] = blend4(A2.x,B2.x,C2.x,D2.x,W00,W01,W10,W11);
    fp[ 9] = blend4(A2.y,B2.y,C2.y,D2.y,W00,W01,W10,W11);
    fp[10] = blend4(A2.z,B2.z,C2.z,D2.z,W00,W01,W10,W11);
    fp[11] = blend4(A2.w,B2.w,C2.w,D2.w,W00,W01,W10,W11);
    fp[12] = blend4(A3.x,B3.x,C3.x,D3.x,W00,W01,W10,W11);
    fp[13] = blend4(A3.y,B3.y,C3.y,D3.y,W00,W01,W10,W11);
    fp[14] = blend4(A3.z,B3.z,C3.z,D3.z,W00,W01,W10,W11);
    fp[15] = blend4(A3.w,B3.w,C3.w,D3.w,W00,W01,W10,W11);

    #pragma unroll
    for (int i = 0; i < 16; i++) shf[(q*16 + i)*181 + s] = fp[i];

    const uint4* CWv = (const uint4*)(wsu + O_CWC2 + cls*256) + q*32;  // cp*2 uint4
    float mid[8] = {0,0,0,0,0,0,0,0};
    #pragma unroll
    for (int i = 0; i < 16; i++) {
      uint4 w0 = CWv[i*2], w1 = CWv[i*2+1];
      h2 f = uh(fp[i]);
      mid[0] = FDOT2(f, uh(w0.x), mid[0]); mid[1] = FDOT2(f, uh(w0.y), mid[1]);
      mid[2] = FDOT2(f, uh(w0.z), mid[2]); mid[3] = FDOT2(f, uh(w0.w), mid[3]);
      mid[4] = FDOT2(f, uh(w1.x), mid[4]); mid[5] = FDOT2(f, uh(w1.y), mid[5]);
      mid[6] = FDOT2(f, uh(w1.z), mid[6]); mid[7] = FDOT2(f, uh(w1.w), mid[7]);
    }
    #pragma unroll
    for (int k = 0; k < 8; k++) mid[k] += __shfl_xor(mid[k], 1);
    shm4[s*4 + q*2 + 0] = pkh(mid[q*4+0], mid[q*4+1]);
    shm4[s*4 + q*2 + 1] = pkh(mid[q*4+2], mid[q*4+3]);
  }
  __syncthreads();

  // ---- tail: pred_o = conv_tw(fc) + conv_W2P(mid) + bias ---- (row-major pixels)
  int half = t >> 7, pi = t & 127;
  int tx = pi & 15, ty = pi >> 4;
  int slots[9];
  #pragma unroll
  for (int dy = 0; dy < 3; dy++)
    #pragma unroll
    for (int dx = 0; dx < 3; dx++)
      slots[dy*3 + dx] = sof[(ty + dy)*18 + (tx + dx)];
  const unsigned* TW2 = wsu + O_TW2;
  float a0, a1, a2;
  if (half == 0) { a0 = ws[O_TB+0]; a1 = ws[O_TB+1]; a2 = ws[O_TB+2]; }
  else           { a0 = 0.0f; a1 = 0.0f; a2 = 0.0f; }
  int cp0 = half*16;
  for (int cpl = 0; cpl < 16; cpl++) {
    int cp = cp0 + cpl;
    #pragma unroll
    for (int j = 0; j < 9; j++) {
      h2 hv = uh(shf[cp*181 + slots[j]]);
      a0 = FDOT2(hv, uh(TW2[(0*9 + j)*32 + cp]), a0);
      a1 = FDOT2(hv, uh(TW2[(1*9 + j)*32 + cp]), a1);
      a2 = FDOT2(hv, uh(TW2[(2*9 + j)*32 + cp]), a2);
    }
  }
  // mid contribution split by j across halves
  {
    int jb = (half == 0) ? 0 : 5;
    int je = (half == 0) ? 5 : 9;
    for (int j = jb; j < je; j++) {
      int sl = slots[j];
      int cl = scls[sl];
      uint4 mv = *(const uint4*)&shm4[sl*4];
      const uint4* Wp = (const uint4*)(wsu + O_W2P) + (cl*9 + j)*3;
      uint4 w0 = Wp[0], w1 = Wp[1], w2 = Wp[2];
      h2 m0 = uh(mv.x), m1 = uh(mv.y), m2 = uh(mv.z), m3 = uh(mv.w);
      a0 = FDOT2(m0, uh(w0.x), a0); a0 = FDOT2(m1, uh(w0.y), a0);
      a0 = FDOT2(m2, uh(w0.z), a0); a0 = FDOT2(m3, uh(w0.w), a0);
      a1 = FDOT2(m0, uh(w1.x), a1); a1 = FDOT2(m1, uh(w1.y), a1);
      a1 = FDOT2(m2, uh(w1.z), a1); a1 = FDOT2(m3, uh(w1.w), a1);
      a2 = FDOT2(m0, uh(w2.x), a2); a2 = FDOT2(m1, uh(w2.y), a2);
      a2 = FDOT2(m2, uh(w2.z), a2); a2 = FDOT2(m3, uh(w2.w), a2);
    }
  }
  if (half == 1) {
    spart[pi*3+0] = a0; spart[pi*3+1] = a1; spart[pi*3+2] = a2;
  }
  __syncthreads();
  if (half == 0) {
    a0 += spart[pi*3+0]; a1 += spart[pi*3+1]; a2 += spart[pi*3+2];
    ((uint2*)pred4)[blk*128 + pi] = make_uint2(pkbf(a0, a1), pkbf(a2, 0.0f));
  }
}

// ==== K3: query gather ====
__global__ __launch_bounds__(256) void k_gather(const void* __restrict__ inp,
                                                const void* __restrict__ coord, const void* __restrict__ cell,
                                                const float* __restrict__ ws, void* __restrict__ outp) {
  bool f32m = sniff_f32(inp);
  const uint2* pred4 = (const uint2*)((const unsigned*)ws + O_PRED);
  int q = blockIdx.x*256 + threadIdx.x;
  float cy, cx, ly, lx;
  if (f32m) {
    float2 c = ((const float2*)coord)[q]; cy = c.x; cx = c.y;
    float2 l = ((const float2*)cell)[q];  ly = l.x; lx = l.y;
  } else {
    unsigned cu = ((const unsigned*)coord)[q]; cy = asf(cu<<16); cx = asf(cu & 0xffff0000u);
    unsigned lu = ((const unsigned*)cell)[q];  ly = asf(lu<<16); lx = asf(lu & 0xffff0000u);
  }
  float gyq = fminf(fmaxf(cy - ly*0.5f + 1e-6f, -1.0f + 1e-6f), 1.0f - 1e-6f);
  float gxq = fminf(fmaxf(cx - lx*0.5f + 1e-6f, -1.0f + 1e-6f), 1.0f - 1e-6f);
  int xi = (int)rintf((gxq + 1.0f)*0.5f*511.0f);
  int yi = (int)rintf((gyq + 1.0f)*0.5f*511.0f);
  xi = min(max(xi, 0), WSZ-1);
  yi = min(max(yi, 0), HS-1);
  // invert block-sorted layout (row-major pixels within tile)
  int row = yi >> 3, col = xi >> 4;
  int xcd = row >> 3;
  int local = (row & 7)*32 + col;
  int blk = local*8 + xcd;
  int pi = (yi & 7)*16 + (xi & 15);
  uint2 d = pred4[blk*128 + pi];
  float v0 = asf(d.x << 16), v1 = asf(d.x & 0xffff0000u), v2 = asf(d.y << 16);
  if (f32m) {
    float* o = (float*)outp;
    o[q*3 + 0] = v0; o[q*3 + 1] = v1; o[q*3 + 2] = v2;
  } else {
    bf16* o = (bf16*)outp;
    o[q*3 + 0] = __float2bfloat16(v0);
    o[q*3 + 1] = __float2bfloat16(v1);
    o[q*3 + 2] = __float2bfloat16(v2);
  }
}

extern "C" void kernel_launch(void* const* d_in, const int* in_sizes, int n_in,
                              void* d_out, int out_size, void* d_ws, size_t ws_size,
                              hipStream_t stream) {
  const void* inp   = d_in[0];
  const void* coord = d_in[1];
  const void* cell  = d_in[2];
  const void* encw  = d_in[3];
  const void* encb  = d_in[4];
  const void* w1    = d_in[5];
  const void* b1    = d_in[6];
  const void* w2    = d_in[7];
  const void* b2    = d_in[8];
  const void* rw    = d_in[9];
  const void* rb    = d_in[10];
  const void* ow    = d_in[11];
  const void* ob    = d_in[12];
  const void* tw    = d_in[13];
  const void* tb    = d_in[14];
  const void* wc    = d_in[15];
  const void* we    = d_in[16];

  float* wsf = (float*)d_ws;
  unsigned* pred4 = (unsigned*)wsf + O_PRED;

  k_prep<<<273, 256, 0, stream>>>(inp, encw, encb, w1, b1, w2, b2, rw, rb, ow, ob, tw, tb, wc, we, wsf);
  k_maintail<<<2048, 256, 0, stream>>>(wsf, pred4);
  k_gather<<<1024, 256, 0, stream>>>(inp, coord, cell, wsf, d_out);
}